// Round 1
// 1025.949 us; speedup vs baseline: 1.0714x; 1.0714x over previous
//
#include <hip/hip_runtime.h>
#include <hip/hip_bf16.h>

// Criss-Cross Attention, MI355X. Round 3:
//  - k_qkv: T2 both-sides XOR swizzle (rule #21): linear LDS dest, inverse-swz
//    global source chunk, swz ds_read -> kills the 16-way bank conflict on
//    the 128B-row Al/Bl tiles (SQ_LDS_BANK_CONFLICT 3.57e7 -> ~0).
//  - epilogue restructure: k_outrow writes bf16 orw (no x read / f32 out
//    write); k_final does the single fused out = gamma*(row + col^T) + x.
//    k_outcol runs before k_outrow so orw aliases dead vt.
// B=8, C=512, C8=64, S=128. All MFMA = 16x16x32 bf16 (verified layouts):
//   a/b frag: M[row = lane&15][k = (lane>>4)*8 + j], D = A * B^T
//   D frag:   D[row = (lane>>4)*4 + reg][col = lane&15]

#define S 128
#define SS 16384
#define C 512
#define C8 64
#define NEG_BIG -1000000000.0f

using short8 = __attribute__((ext_vector_type(8))) short;
using f32x4  = __attribute__((ext_vector_type(4))) float;

#define GPTR(p) ((const __attribute__((address_space(1))) void*)(p))
#define LPTR(p) ((__attribute__((address_space(3))) void*)(p))

__device__ __forceinline__ unsigned short f2b(float f){
  union { float f; unsigned u; } v; v.f = f;
  unsigned r = (v.u + 0x7fffu + ((v.u >> 16) & 1u)) >> 16;
  return (unsigned short)r;
}
__device__ __forceinline__ float b2f(unsigned short h){
  union { unsigned u; float f; } v; v.u = ((unsigned)h) << 16;
  return v.f;
}

// ---------------- K0a: pack Wq|Wk|Wv -> wall[640][512] bf16 ----------------
__global__ __launch_bounds__(256) void k_pack_w(
    const float* __restrict__ Wq, const float* __restrict__ Wk,
    const float* __restrict__ Wv, unsigned short* __restrict__ wall){
  int i = blockIdx.x * 256 + threadIdx.x;
  if (i >= 640 * C) return;
  int co = i >> 9, ci = i & (C - 1);
  float v;
  if (co < 64)        v = Wq[co * C + ci];
  else if (co < 128)  v = Wk[(co - 64) * C + ci];
  else                v = Wv[(co - 128) * C + ci];
  wall[i] = f2b(v);
}

// ---------------- K0b: x (f32, [b][ci][w][h]) -> xp (bf16, [b][w][h][ci]) ----
__global__ __launch_bounds__(256) void k_xp(
    const float* __restrict__ x, unsigned short* __restrict__ xp){
  __shared__ unsigned short T[128 * 130] __attribute__((aligned(16)));
  int blk = blockIdx.x;                 // ((b*128 + w)*4 + ct)
  int ct = blk & 3; int bw = blk >> 2;
  int w = bw & 127; int b = bw >> 7;
  int tid = threadIdx.x;
  int ci0 = ct * 128;
  const float* xb = x + ((size_t)(b * C + ci0) * S + w) * S;  // + cc*SS + h
  #pragma unroll
  for (int p = 0; p < 16; ++p){
    int idx = p * 256 + tid;            // 0..4095
    int cc = idx >> 5;
    int h4 = (idx & 31) * 4;
    float4 v = *(const float4*)(xb + (size_t)cc * SS + h4);
    unsigned* d = (unsigned*)&T[cc * 130 + h4];
    d[0] = (unsigned)f2b(v.x) | ((unsigned)f2b(v.y) << 16);
    d[1] = (unsigned)f2b(v.z) | ((unsigned)f2b(v.w) << 16);
  }
  __syncthreads();
  unsigned short* xpb = xp + (size_t)(b * S + w) * S * C + ci0;
  #pragma unroll
  for (int p = 0; p < 8; ++p){
    int idx = p * 256 + tid;            // 0..2047
    int h  = idx >> 4;
    int ch = (idx & 15) * 8;            // cc chunk
    unsigned short tmp[8] __attribute__((aligned(16)));
    #pragma unroll
    for (int j = 0; j < 8; ++j) tmp[j] = T[(ch + j) * 130 + h];
    *(uint4*)(xpb + (size_t)h * C + ch) = *(uint4*)tmp;
  }
}

// ---------------- K1: qkv projection GEMM (m97-style + T2 swizzle) ----------
// Swizzled grid (5120): pxsub=blk&7, t=blk>>3, cot=t%5, pxg=t/5, px=pxg*8+pxsub
// -> the 5 cot-blocks of one px-tile are temporally adjacent + same XCD.
// LDS swizzle: chunk c (16B) of row r holds global chunk c^(r&7); ds_read
// applies the same XOR -> 16-way bank conflict becomes 2-way (free).
__global__ __launch_bounds__(256) void k_qkv(
    const unsigned short* __restrict__ xp, const unsigned short* __restrict__ wall,
    const float* __restrict__ bq, const float* __restrict__ bk,
    const float* __restrict__ bv,
    unsigned short* __restrict__ qp, unsigned short* __restrict__ kp,
    unsigned short* __restrict__ vb){
  __shared__ unsigned short sm[17408] __attribute__((aligned(16)));  // 34816 B
  unsigned short* Al = sm;              // [128][64] (chunk-swizzled)
  unsigned short* Bl = sm + 8192;       // [128][64] (chunk-swizzled)
  unsigned short* Dl = sm;              // alias: [128][136]
  int blk = blockIdx.x;
  int pxsub = blk & 7; int t = blk >> 3;
  int cot = t % 5; int pxg = t / 5;
  int pxt = pxg * 8 + pxsub;            // 0..1023
  int w = pxt & 127, b = pxt >> 7;
  int tid = threadIdx.x, lane = tid & 63, wid = tid >> 6;
  int qd = lane >> 4, ln = lane & 15;
  const unsigned short* asrc0 = wall + (size_t)cot * 128 * C;
  const unsigned short* bsrc0 = xp + (size_t)pxt * 128 * C;
  f32x4 acc[4][4];
  #pragma unroll
  for (int i = 0; i < 4; ++i)
    #pragma unroll
    for (int j = 0; j < 4; ++j) acc[i][j] = (f32x4){0.f, 0.f, 0.f, 0.f};

  for (int kw = 0; kw < 8; ++kw){
    __syncthreads();
    const unsigned short* asrc = asrc0 + kw * 64;
    const unsigned short* bsrc = bsrc0 + kw * 64;
    #pragma unroll
    for (int p = 0; p < 4; ++p){
      int gi = p * 256 + tid;           // 0..1023
      int row = gi >> 3, cc = gi & 7;
      int kc = (cc ^ (row & 7)) * 8;    // inverse-swizzled global chunk
      __builtin_amdgcn_global_load_lds(GPTR(asrc + (size_t)row * C + kc),
                                       LPTR((char*)Al + gi * 16), 16, 0, 0);
      __builtin_amdgcn_global_load_lds(GPTR(bsrc + (size_t)row * C + kc),
                                       LPTR((char*)Bl + gi * 16), 16, 0, 0);
    }
    __syncthreads();
    #pragma unroll
    for (int ks = 0; ks < 2; ++ks){
      int ch8 = (((ks * 4 + qd) ^ (ln & 7)) * 8);   // swizzled read chunk
      short8 af[4], bfr[4];
      #pragma unroll
      for (int i = 0; i < 4; ++i)
        af[i] = *(const short8*)&Al[(((wid & 1) * 4 + i) * 16 + ln) * 64 + ch8];
      #pragma unroll
      for (int j = 0; j < 4; ++j)
        bfr[j] = *(const short8*)&Bl[(((wid >> 1) * 4 + j) * 16 + ln) * 64 + ch8];
      #pragma unroll
      for (int i = 0; i < 4; ++i)
        #pragma unroll
        for (int j = 0; j < 4; ++j)
          acc[i][j] = __builtin_amdgcn_mfma_f32_16x16x32_bf16(af[i], bfr[j], acc[i][j], 0, 0, 0);
    }
  }
  __syncthreads();
  // bias + pack into Dl[co][px] (pitch 136), then coalesced global stores
  float bias_[4][4];
  #pragma unroll
  for (int i = 0; i < 4; ++i){
    int co_l0 = ((wid & 1) * 4 + i) * 16 + qd * 4;
    #pragma unroll
    for (int r = 0; r < 4; ++r){
      int co_l = co_l0 + r;
      bias_[i][r] = (cot == 0) ? (co_l < 64 ? bq[co_l] : bk[co_l - 64])
                               : bv[(cot - 1) * 128 + co_l];
    }
  }
  #pragma unroll
  for (int i = 0; i < 4; ++i){
    int co_l0 = ((wid & 1) * 4 + i) * 16 + qd * 4;
    #pragma unroll
    for (int j = 0; j < 4; ++j){
      int pxl = ((wid >> 1) * 4 + j) * 16 + ln;
      #pragma unroll
      for (int r = 0; r < 4; ++r)
        Dl[(co_l0 + r) * 136 + pxl] = f2b(acc[i][j][r] + bias_[i][r]);
    }
  }
  __syncthreads();
  if (cot == 0){
    unsigned short* qb = qp + (size_t)(b * S + w) * S * C8;
    unsigned short* kb = kp + (size_t)(b * S + w) * S * C8;
    #pragma unroll
    for (int p = 0; p < 4; ++p){
      int idx = p * 256 + tid;          // 0..1023
      int cch = idx & 7, hh = idx >> 3;
      unsigned short tq[8] __attribute__((aligned(16)));
      unsigned short tk[8] __attribute__((aligned(16)));
      #pragma unroll
      for (int jj = 0; jj < 8; ++jj){
        tq[jj] = Dl[(cch * 8 + jj) * 136 + hh];
        tk[jj] = Dl[(64 + cch * 8 + jj) * 136 + hh];
      }
      *(uint4*)(qb + (size_t)hh * C8 + cch * 8) = *(uint4*)tq;
      *(uint4*)(kb + (size_t)hh * C8 + cch * 8) = *(uint4*)tk;
    }
  } else {
    unsigned short* vbb = vb + ((size_t)(b * C + (cot - 1) * 128) * S + w) * S;
    #pragma unroll
    for (int p = 0; p < 8; ++p){
      int idx = p * 256 + tid;          // 0..2047
      int c_l = idx >> 4, hc = (idx & 15) * 8;
      uint4 v = *(const uint4*)&Dl[c_l * 136 + hc];
      *(uint4*)(vbb + (size_t)c_l * SS + hc) = v;
    }
  }
}

// ---------------- K2: vb [b][c][w][h] -> vt [b][c][h][w] ----------------
__global__ __launch_bounds__(256) void k_tv(
    const unsigned short* __restrict__ vb, unsigned short* __restrict__ vt){
  __shared__ unsigned short T[128 * 130] __attribute__((aligned(16)));
  int bc = blockIdx.x;                  // b*C + c
  const unsigned short* src = vb + (size_t)bc * SS;
  unsigned short* dst = vt + (size_t)bc * SS;
  int tid = threadIdx.x;
  #pragma unroll
  for (int p = 0; p < 8; ++p){
    int idx = p * 256 + tid;            // 0..2047
    int wv = idx >> 4, ch = (idx & 15) * 8;
    uint4 v = *(const uint4*)(src + wv * S + ch);
    unsigned* d = (unsigned*)&T[wv * 130 + ch];
    d[0] = v.x; d[1] = v.y; d[2] = v.z; d[3] = v.w;
  }
  __syncthreads();
  #pragma unroll
  for (int p = 0; p < 8; ++p){
    int idx = p * 256 + tid;
    int h = idx >> 4, ch = (idx & 15) * 8;
    unsigned short tmp[8] __attribute__((aligned(16)));
    #pragma unroll
    for (int j = 0; j < 8; ++j) tmp[j] = T[(ch + j) * 130 + h];
    *(uint4*)(dst + h * S + ch) = *(uint4*)tmp;
  }
}

// ---------------- K3: column scores e_col[b][w][h][u] (masked diag), bf16 ---
__global__ __launch_bounds__(256) void k_ecol(
    const unsigned short* __restrict__ qp, const unsigned short* __restrict__ kp,
    unsigned short* __restrict__ eca){
  __shared__ unsigned short Aq[128 * 72] __attribute__((aligned(16)));
  __shared__ unsigned short Bk[128 * 72] __attribute__((aligned(16)));
  int blk = blockIdx.x; int h = blk & 127, b = blk >> 7;
  int tid = threadIdx.x, lane = tid & 63, wid = tid >> 6;
  int qd = lane >> 4, ln = lane & 15;
  #pragma unroll
  for (int p = 0; p < 4; ++p){
    int idx = p * 256 + tid;
    int row = idx >> 3, ch = (idx & 7) * 8;
    *(uint4*)&Aq[row * 72 + ch] = *(const uint4*)(qp + ((size_t)(b * S + row) * S + h) * C8 + ch);
    *(uint4*)&Bk[row * 72 + ch] = *(const uint4*)(kp + ((size_t)(b * S + row) * S + h) * C8 + ch);
  }
  __syncthreads();
  f32x4 acc[4][4];
  #pragma unroll
  for (int i = 0; i < 4; ++i)
    #pragma unroll
    for (int j = 0; j < 4; ++j) acc[i][j] = (f32x4){0.f, 0.f, 0.f, 0.f};
  #pragma unroll
  for (int ks = 0; ks < 2; ++ks){
    int ko = ks * 32 + qd * 8;
    short8 af[4], bfr[4];
    #pragma unroll
    for (int i = 0; i < 4; ++i)
      af[i] = *(const short8*)&Aq[(((wid & 1) * 4 + i) * 16 + ln) * 72 + ko];
    #pragma unroll
    for (int j = 0; j < 4; ++j)
      bfr[j] = *(const short8*)&Bk[(((wid >> 1) * 4 + j) * 16 + ln) * 72 + ko];
    #pragma unroll
    for (int i = 0; i < 4; ++i)
      #pragma unroll
      for (int j = 0; j < 4; ++j)
        acc[i][j] = __builtin_amdgcn_mfma_f32_16x16x32_bf16(af[i], bfr[j], acc[i][j], 0, 0, 0);
  }
  #pragma unroll
  for (int i = 0; i < 4; ++i){
    int w0 = ((wid & 1) * 4 + i) * 16 + qd * 4;
    #pragma unroll
    for (int j = 0; j < 4; ++j){
      int ug = ((wid >> 1) * 4 + j) * 16 + ln;
      #pragma unroll
      for (int r = 0; r < 4; ++r){
        int wg = w0 + r;
        float val = acc[i][j][r];
        if (wg == ug) val = NEG_BIG;
        eca[((size_t)(b * S + wg) * S + h) * S + ug] = f2b(val);
      }
    }
  }
}

// ------- K4: row scores + joint softmax; ac overwrites eca in place; ar out --
__global__ __launch_bounds__(256) void k_erow_softmax(
    const unsigned short* __restrict__ qp, const unsigned short* __restrict__ kp,
    unsigned short* __restrict__ eca, unsigned short* __restrict__ ar){
  __shared__ char sm[36864] __attribute__((aligned(16)));
  unsigned short* Aq = (unsigned short*)sm;              // [128][72]
  unsigned short* Bk = (unsigned short*)(sm + 18432);    // [128][72]
  unsigned short* El = (unsigned short*)sm;              // alias: [128][136] bf16
  float* redm = (float*)(sm + 34816);                    // [256]
  float* reds = (float*)(sm + 35840);                    // [256]
  int blk = blockIdx.x; int w = blk & 127, b = blk >> 7;
  int tid = threadIdx.x, lane = tid & 63, wid = tid >> 6;
  int qd = lane >> 4, ln = lane & 15;
  size_t tb = (size_t)(b * S + w) * SS;                  // tile base (elems)
  {
    const unsigned short* qsrc = qp + (size_t)(b * S + w) * S * C8;
    const unsigned short* ksrc = kp + (size_t)(b * S + w) * S * C8;
    #pragma unroll
    for (int p = 0; p < 4; ++p){
      int idx = p * 256 + tid;
      int row = idx >> 3, ch = (idx & 7) * 8;
      *(uint4*)&Aq[row * 72 + ch] = *(const uint4*)(qsrc + row * C8 + ch);
      *(uint4*)&Bk[row * 72 + ch] = *(const uint4*)(ksrc + row * C8 + ch);
    }
  }
  __syncthreads();
  f32x4 acc[4][4];
  #pragma unroll
  for (int i = 0; i < 4; ++i)
    #pragma unroll
    for (int j = 0; j < 4; ++j) acc[i][j] = (f32x4){0.f, 0.f, 0.f, 0.f};
  #pragma unroll
  for (int ks = 0; ks < 2; ++ks){
    int ko = ks * 32 + qd * 8;
    short8 af[4], bfr[4];
    #pragma unroll
    for (int i = 0; i < 4; ++i)
      af[i] = *(const short8*)&Aq[(((wid & 1) * 4 + i) * 16 + ln) * 72 + ko];
    #pragma unroll
    for (int j = 0; j < 4; ++j)
      bfr[j] = *(const short8*)&Bk[(((wid >> 1) * 4 + j) * 16 + ln) * 72 + ko];
    #pragma unroll
    for (int i = 0; i < 4; ++i)
      #pragma unroll
      for (int j = 0; j < 4; ++j)
        acc[i][j] = __builtin_amdgcn_mfma_f32_16x16x32_bf16(af[i], bfr[j], acc[i][j], 0, 0, 0);
  }
  __syncthreads();     // done with Aq/Bk; El may now alias them
  #pragma unroll
  for (int i = 0; i < 4; ++i){
    int h0 = ((wid & 1) * 4 + i) * 16 + qd * 4;
    #pragma unroll
    for (int j = 0; j < 4; ++j){
      int ul = ((wid >> 1) * 4 + j) * 16 + ln;
      #pragma unroll
      for (int r = 0; r < 4; ++r)
        El[(h0 + r) * 136 + ul] = f2b(acc[i][j][r]);
    }
  }
  __syncthreads();
  // softmax over 256 = [col(128 from eca) | row(128 from El)] per h
  int h = tid >> 1, half = tid & 1;
  const uint4* src4 = (half == 0) ? (const uint4*)(eca + tb + (size_t)h * S)
                                  : (const uint4*)&El[h * 136];
  float mx = -3.0e38f;
  #pragma unroll 4
  for (int u = 0; u < 16; ++u){
    uint4 v = src4[u];
    const unsigned short* e = (const unsigned short*)&v;
    #pragma unroll
    for (int jj = 0; jj < 8; ++jj) mx = fmaxf(mx, b2f(e[jj]));
  }
  redm[tid] = mx;
  __syncthreads();
  float m = fmaxf(mx, redm[tid ^ 1]);
  float s = 0.f;
  #pragma unroll 4
  for (int u = 0; u < 16; ++u){
    uint4 v = src4[u];
    const unsigned short* e = (const unsigned short*)&v;
    #pragma unroll
    for (int jj = 0; jj < 8; ++jj) s += __expf(b2f(e[jj]) - m);
  }
  reds[tid] = s;
  __syncthreads();
  float inv = 1.0f / (s + reds[tid ^ 1]);
  uint4* dst4 = (half == 0) ? (uint4*)(eca + tb + (size_t)h * S)
                            : (uint4*)(ar + tb + (size_t)h * S);
  #pragma unroll 4
  for (int u = 0; u < 16; ++u){
    uint4 v = src4[u];
    const unsigned short* e = (const unsigned short*)&v;
    unsigned short o[8] __attribute__((aligned(16)));
    #pragma unroll
    for (int jj = 0; jj < 8; ++jj) o[jj] = f2b(__expf(b2f(e[jj]) - m) * inv);
    dst4[u] = *(uint4*)o;
  }
}

// ------- K5: out_row GEMM -> orw[b][c][w][h] bf16 (raw acc, no gamma/x) ------
__global__ __launch_bounds__(256) void k_outrow(
    const unsigned short* __restrict__ vb, const unsigned short* __restrict__ ar,
    unsigned short* __restrict__ orw){
  __shared__ unsigned short Av[128 * 72] __attribute__((aligned(16)));
  __shared__ unsigned short Ba[128 * 72] __attribute__((aligned(16)));
  int blk = blockIdx.x;                 // ((b*128+w)*4 + ct)
  int ct = blk & 3; int bw = blk >> 2;
  int w = bw & 127, b = bw >> 7;
  int tid = threadIdx.x, lane = tid & 63, wid = tid >> 6;
  int qd = lane >> 4, ln = lane & 15;
  size_t tb = (size_t)(b * S + w) * SS;
  f32x4 acc[4][4];
  #pragma unroll
  for (int i = 0; i < 4; ++i)
    #pragma unroll
    for (int j = 0; j < 4; ++j) acc[i][j] = (f32x4){0.f, 0.f, 0.f, 0.f};
  for (int kw = 0; kw < 2; ++kw){
    __syncthreads();
    #pragma unroll
    for (int p = 0; p < 4; ++p){
      int idx = p * 256 + tid;
      int row = idx >> 3, ch = (idx & 7) * 8;
      *(uint4*)&Av[row * 72 + ch] =
        *(const uint4*)(vb + ((size_t)(b * C + ct * 128 + row) * S + w) * S + kw * 64 + ch);
      *(uint4*)&Ba[row * 72 + ch] =
        *(const uint4*)(ar + tb + (size_t)row * S + kw * 64 + ch);
    }
    __syncthreads();
    #pragma unroll
    for (int ks = 0; ks < 2; ++ks){
      int ko = ks * 32 + qd * 8;
      short8 af[4], bfr[4];
      #pragma unroll
      for (int i = 0; i < 4; ++i)
        af[i] = *(const short8*)&Av[(((wid & 1) * 4 + i) * 16 + ln) * 72 + ko];
      #pragma unroll
      for (int j = 0; j < 4; ++j)
        bfr[j] = *(const short8*)&Ba[(((wid >> 1) * 4 + j) * 16 + ln) * 72 + ko];
      #pragma unroll
      for (int i = 0; i < 4; ++i)
        #pragma unroll
        for (int j = 0; j < 4; ++j)
          acc[i][j] = __builtin_amdgcn_mfma_f32_16x16x32_bf16(af[i], bfr[j], acc[i][j], 0, 0, 0);
    }
  }
  #pragma unroll
  for (int i = 0; i < 4; ++i){
    int c0 = ((wid & 1) * 4 + i) * 16 + qd * 4;
    #pragma unroll
    for (int j = 0; j < 4; ++j){
      int hl = ((wid >> 1) * 4 + j) * 16 + ln;
      #pragma unroll
      for (int r = 0; r < 4; ++r){
        int cg = ct * 128 + c0 + r;
        orw[((size_t)(b * C + cg) * S + w) * S + hl] = f2b(acc[i][j][r]);
      }
    }
  }
}

// ------- K6: out_col -> oct[b][h][c][w] bf16 ----------------
__global__ __launch_bounds__(256) void k_outcol(
    const unsigned short* __restrict__ vt, const unsigned short* __restrict__ eca,
    unsigned short* __restrict__ oct){
  __shared__ unsigned short Av[128 * 72] __attribute__((aligned(16)));
  __shared__ unsigned short Ba[128 * 72] __attribute__((aligned(16)));
  int blk = blockIdx.x;                 // ((b*128+h)*4 + ct)
  int ct = blk & 3; int bh = blk >> 2;
  int h = bh & 127, b = bh >> 7;
  int tid = threadIdx.x, lane = tid & 63, wid = tid >> 6;
  int qd = lane >> 4, ln = lane & 15;
  f32x4 acc[4][4];
  #pragma unroll
  for (int i = 0; i < 4; ++i)
    #pragma unroll
    for (int j = 0; j < 4; ++j) acc[i][j] = (f32x4){0.f, 0.f, 0.f, 0.f};
  for (int kw = 0; kw < 2; ++kw){
    __syncthreads();
    #pragma unroll
    for (int p = 0; p < 4; ++p){
      int idx = p * 256 + tid;
      int row = idx >> 3, ch = (idx & 7) * 8;
      *(uint4*)&Av[row * 72 + ch] =
        *(const uint4*)(vt + ((size_t)(b * C + ct * 128 + row) * S + h) * S + kw * 64 + ch);
      *(uint4*)&Ba[row * 72 + ch] =
        *(const uint4*)(eca + ((size_t)(b * S + row) * S + h) * S + kw * 64 + ch);
    }
    __syncthreads();
    #pragma unroll
    for (int ks = 0; ks < 2; ++ks){
      int ko = ks * 32 + qd * 8;
      short8 af[4], bfr[4];
      #pragma unroll
      for (int i = 0; i < 4; ++i)
        af[i] = *(const short8*)&Av[(((wid & 1) * 4 + i) * 16 + ln) * 72 + ko];
      #pragma unroll
      for (int j = 0; j < 4; ++j)
        bfr[j] = *(const short8*)&Ba[(((wid >> 1) * 4 + j) * 16 + ln) * 72 + ko];
      #pragma unroll
      for (int i = 0; i < 4; ++i)
        #pragma unroll
        for (int j = 0; j < 4; ++j)
          acc[i][j] = __builtin_amdgcn_mfma_f32_16x16x32_bf16(af[i], bfr[j], acc[i][j], 0, 0, 0);
    }
  }
  #pragma unroll
  for (int i = 0; i < 4; ++i){
    int c0 = ((wid & 1) * 4 + i) * 16 + qd * 4;
    #pragma unroll
    for (int j = 0; j < 4; ++j){
      int wl = ((wid >> 1) * 4 + j) * 16 + ln;
      #pragma unroll
      for (int r = 0; r < 4; ++r){
        int cg = ct * 128 + c0 + r;
        oct[((size_t)(b * S + h) * C + cg) * S + wl] = f2b(acc[i][j][r]);
      }
    }
  }
}

// ------- K7: out = gamma * (orw + transpose(oct)) + x  (single out write) ----
__global__ __launch_bounds__(256) void k_final(
    const unsigned short* __restrict__ oct, const unsigned short* __restrict__ orw,
    const float* __restrict__ x, const float* __restrict__ gamma,
    float* __restrict__ out){
  __shared__ unsigned short T[128 * 130] __attribute__((aligned(16)));
  int blk = blockIdx.x;                 // b*C + c
  int c = blk & 511, b = blk >> 9;
  int tid = threadIdx.x;
  float g = gamma[0];
  #pragma unroll
  for (int p = 0; p < 8; ++p){
    int idx = p * 256 + tid;
    int hh = idx >> 4, ch = (idx & 15) * 8;
    uint4 v = *(const uint4*)(oct + ((size_t)(b * S + hh) * C + c) * S + ch);
    unsigned* d = (unsigned*)&T[hh * 130 + ch];
    d[0] = v.x; d[1] = v.y; d[2] = v.z; d[3] = v.w;
  }
  __syncthreads();
  #pragma unroll
  for (int p = 0; p < 8; ++p){
    int idx = p * 256 + tid;
    int wv = idx >> 4, hch = (idx & 15) * 8;
    size_t o = ((size_t)(b * C + c) * S + wv) * S + hch;
    uint4 rv = *(const uint4*)(orw + o);
    const unsigned short* rr = (const unsigned short*)&rv;
    float4 x0 = *(const float4*)(x + o);
    float4 x1 = *(const float4*)(x + o + 4);
    float4 o0, o1;
    o0.x = g * (b2f(rr[0]) + b2f(T[(hch + 0) * 130 + wv])) + x0.x;
    o0.y = g * (b2f(rr[1]) + b2f(T[(hch + 1) * 130 + wv])) + x0.y;
    o0.z = g * (b2f(rr[2]) + b2f(T[(hch + 2) * 130 + wv])) + x0.z;
    o0.w = g * (b2f(rr[3]) + b2f(T[(hch + 3) * 130 + wv])) + x0.w;
    o1.x = g * (b2f(rr[4]) + b2f(T[(hch + 4) * 130 + wv])) + x1.x;
    o1.y = g * (b2f(rr[5]) + b2f(T[(hch + 5) * 130 + wv])) + x1.y;
    o1.z = g * (b2f(rr[6]) + b2f(T[(hch + 6) * 130 + wv])) + x1.z;
    o1.w = g * (b2f(rr[7]) + b2f(T[(hch + 7) * 130 + wv])) + x1.w;
    *(float4*)(out + o) = o0;
    *(float4*)(out + o + 4) = o1;
  }
}

extern "C" void kernel_launch(void* const* d_in, const int* in_sizes, int n_in,
                              void* d_out, int out_size, void* d_ws, size_t ws_size,
                              hipStream_t stream){
  const float* x     = (const float*)d_in[0];
  const float* Wq    = (const float*)d_in[1];
  const float* bq    = (const float*)d_in[2];
  const float* Wk    = (const float*)d_in[3];
  const float* bk    = (const float*)d_in[4];
  const float* Wv    = (const float*)d_in[5];
  const float* bv    = (const float*)d_in[6];
  const float* gamma = (const float*)d_in[7];
  float* out = (float*)d_out;
  char* ws = (char*)d_ws;

  const size_t OFF_WALL = 0;
  const size_t OFF_XP   = 1ull << 20;                    // 134,217,728
  const size_t OFF_QP   = OFF_XP  + 134217728ull;        // 16,777,216
  const size_t OFF_KP   = OFF_QP  + 16777216ull;         // 16,777,216
  const size_t OFF_VB   = OFF_KP  + 16777216ull;         // 134,217,728
  const size_t OFF_VT   = OFF_VB  + 134217728ull;        // 134,217,728
  const size_t OFF_ECA  = OFF_VT  + 134217728ull;        // 33,554,432
  const size_t OFF_AR   = OFF_ECA + 33554432ull;         // 33,554,432
  const size_t OFF_OCT  = OFF_XP;                        // alias: xp dead after k_qkv
  const size_t OFF_ORW  = OFF_VT;                        // alias: vt dead after k_outcol
  const size_t NEED     = OFF_AR + 33554432ull;          // ~481 MiB
  if (ws_size < NEED) return;                            // cannot run; fail cleanly

  unsigned short* wall = (unsigned short*)(ws + OFF_WALL);
  unsigned short* xp   = (unsigned short*)(ws + OFF_XP);
  unsigned short* qp   = (unsigned short*)(ws + OFF_QP);
  unsigned short* kp   = (unsigned short*)(ws + OFF_KP);
  unsigned short* vb   = (unsigned short*)(ws + OFF_VB);
  unsigned short* vt   = (unsigned short*)(ws + OFF_VT);
  unsigned short* eca  = (unsigned short*)(ws + OFF_ECA);
  unsigned short* ar   = (unsigned short*)(ws + OFF_AR);
  unsigned short* oct  = (unsigned short*)(ws + OFF_OCT);
  unsigned short* orw  = (unsigned short*)(ws + OFF_ORW);

  k_pack_w      <<<1280, 256, 0, stream>>>(Wq, Wk, Wv, wall);
  k_xp          <<<4096, 256, 0, stream>>>(x, xp);
  k_qkv         <<<5120, 256, 0, stream>>>(xp, wall, bq, bk, bv, qp, kp, vb);
  k_tv          <<<4096, 256, 0, stream>>>(vb, vt);
  k_ecol        <<<1024, 256, 0, stream>>>(qp, kp, eca);
  k_erow_softmax<<<1024, 256, 0, stream>>>(qp, kp, eca, ar);
  k_outcol      <<<4096, 256, 0, stream>>>(vt, eca, oct);      // before k_outrow: orw aliases vt
  k_outrow      <<<4096, 256, 0, stream>>>(vb, ar, orw);
  k_final       <<<4096, 256, 0, stream>>>(oct, orw, x, gamma, out);
}

// Round 2
// 987.560 us; speedup vs baseline: 1.1130x; 1.0389x over previous
//
#include <hip/hip_runtime.h>
#include <hip/hip_bf16.h>

// Criss-Cross Attention, MI355X. Round 4:
//  - k_qkv: minimum 2-phase prefetch pipeline (T3 recipe): full double-buffer
//    of A+B tiles (65536 B LDS), stage(kw+1) issued BEFORE compute(kw), ONE
//    __syncthreads per K-step (its vmcnt(0) drain is the publish point ->
//    race-clean, no inline-asm waits). T2 chunk-swizzle retained. T5 setprio
//    around the MFMA cluster.
//  - epilogue (Round 3): k_outrow writes bf16 orw; k_final fuses
//    out = gamma*(row + col^T) + x in a single pass.
// B=8, C=512, C8=64, S=128. All MFMA = 16x16x32 bf16 (verified layouts):
//   a/b frag: M[row = lane&15][k = (lane>>4)*8 + j], D = A * B^T
//   D frag:   D[row = (lane>>4)*4 + reg][col = lane&15]

#define S 128
#define SS 16384
#define C 512
#define C8 64
#define NEG_BIG -1000000000.0f

using short8 = __attribute__((ext_vector_type(8))) short;
using f32x4  = __attribute__((ext_vector_type(4))) float;

#define GPTR(p) ((const __attribute__((address_space(1))) void*)(p))
#define LPTR(p) ((__attribute__((address_space(3))) void*)(p))

__device__ __forceinline__ unsigned short f2b(float f){
  union { float f; unsigned u; } v; v.f = f;
  unsigned r = (v.u + 0x7fffu + ((v.u >> 16) & 1u)) >> 16;
  return (unsigned short)r;
}
__device__ __forceinline__ float b2f(unsigned short h){
  union { unsigned u; float f; } v; v.u = ((unsigned)h) << 16;
  return v.f;
}

// stage one [128][64] bf16 tile (row stride C) into LDS, chunk-swizzled:
// LDS chunk gi (16B) receives global chunk (gi&7)^(row&7) of row gi>>3.
// dest is linear (wave-uniform base + lane*16) as global_load_lds requires.
__device__ __forceinline__ void stage_tile64(unsigned short* dst,
    const unsigned short* src, int tid){
  #pragma unroll
  for (int p = 0; p < 4; ++p){
    int gi = p * 256 + tid;             // 0..1023
    int row = gi >> 3, cc = gi & 7;
    int kc = (cc ^ (row & 7)) * 8;      // inverse-swizzled global chunk
    __builtin_amdgcn_global_load_lds(GPTR(src + (size_t)row * C + kc),
                                     LPTR((char*)dst + gi * 16), 16, 0, 0);
  }
}

// ---------------- K0a: pack Wq|Wk|Wv -> wall[640][512] bf16 ----------------
__global__ __launch_bounds__(256) void k_pack_w(
    const float* __restrict__ Wq, const float* __restrict__ Wk,
    const float* __restrict__ Wv, unsigned short* __restrict__ wall){
  int i = blockIdx.x * 256 + threadIdx.x;
  if (i >= 640 * C) return;
  int co = i >> 9, ci = i & (C - 1);
  float v;
  if (co < 64)        v = Wq[co * C + ci];
  else if (co < 128)  v = Wk[(co - 64) * C + ci];
  else                v = Wv[(co - 128) * C + ci];
  wall[i] = f2b(v);
}

// ---------------- K0b: x (f32, [b][ci][w][h]) -> xp (bf16, [b][w][h][ci]) ----
__global__ __launch_bounds__(256) void k_xp(
    const float* __restrict__ x, unsigned short* __restrict__ xp){
  __shared__ unsigned short T[128 * 130] __attribute__((aligned(16)));
  int blk = blockIdx.x;                 // ((b*128 + w)*4 + ct)
  int ct = blk & 3; int bw = blk >> 2;
  int w = bw & 127; int b = bw >> 7;
  int tid = threadIdx.x;
  int ci0 = ct * 128;
  const float* xb = x + ((size_t)(b * C + ci0) * S + w) * S;  // + cc*SS + h
  #pragma unroll
  for (int p = 0; p < 16; ++p){
    int idx = p * 256 + tid;            // 0..4095
    int cc = idx >> 5;
    int h4 = (idx & 31) * 4;
    float4 v = *(const float4*)(xb + (size_t)cc * SS + h4);
    unsigned* d = (unsigned*)&T[cc * 130 + h4];
    d[0] = (unsigned)f2b(v.x) | ((unsigned)f2b(v.y) << 16);
    d[1] = (unsigned)f2b(v.z) | ((unsigned)f2b(v.w) << 16);
  }
  __syncthreads();
  unsigned short* xpb = xp + (size_t)(b * S + w) * S * C + ci0;
  #pragma unroll
  for (int p = 0; p < 8; ++p){
    int idx = p * 256 + tid;            // 0..2047
    int h  = idx >> 4;
    int ch = (idx & 15) * 8;            // cc chunk
    unsigned short tmp[8] __attribute__((aligned(16)));
    #pragma unroll
    for (int j = 0; j < 8; ++j) tmp[j] = T[(ch + j) * 130 + h];
    *(uint4*)(xpb + (size_t)h * C + ch) = *(uint4*)tmp;
  }
}

// ---------------- K1: qkv projection GEMM (2-phase dbuf prefetch) ----------
// Swizzled grid (5120): pxsub=blk&7, t=blk>>3, cot=t%5, pxg=t/5, px=pxg*8+pxsub
// -> the 5 cot-blocks of one px-tile are temporally adjacent + same XCD.
__global__ __launch_bounds__(256) void k_qkv(
    const unsigned short* __restrict__ xp, const unsigned short* __restrict__ wall,
    const float* __restrict__ bq, const float* __restrict__ bk,
    const float* __restrict__ bv,
    unsigned short* __restrict__ qp, unsigned short* __restrict__ kp,
    unsigned short* __restrict__ vb){
  __shared__ unsigned short sm[32768] __attribute__((aligned(16)));  // 65536 B
  // buf k (k=0,1): A at sm + k*16384, B at sm + k*16384 + 8192 (each [128][64])
  unsigned short* Dl = sm;              // alias: [128][136] (17408 shorts)
  int blk = blockIdx.x;
  int pxsub = blk & 7; int t = blk >> 3;
  int cot = t % 5; int pxg = t / 5;
  int pxt = pxg * 8 + pxsub;            // 0..1023
  int w = pxt & 127, b = pxt >> 7;
  int tid = threadIdx.x, lane = tid & 63, wid = tid >> 6;
  int qd = lane >> 4, ln = lane & 15;
  const unsigned short* asrc0 = wall + (size_t)cot * 128 * C;
  const unsigned short* bsrc0 = xp + (size_t)pxt * 128 * C;
  f32x4 acc[4][4];
  #pragma unroll
  for (int i = 0; i < 4; ++i)
    #pragma unroll
    for (int j = 0; j < 4; ++j) acc[i][j] = (f32x4){0.f, 0.f, 0.f, 0.f};

  // prologue: stage kw=0 into buf0
  stage_tile64(sm,        asrc0, tid);
  stage_tile64(sm + 8192, bsrc0, tid);
  __syncthreads();                      // drains vmcnt -> buf0 published

  for (int kw = 0; kw < 8; ++kw){
    unsigned short* Acur = sm + (kw & 1) * 16384;
    unsigned short* Bcur = Acur + 8192;
    if (kw < 7){                        // issue next-tile stage BEFORE compute
      unsigned short* Anxt = sm + ((kw + 1) & 1) * 16384;
      stage_tile64(Anxt,        asrc0 + (kw + 1) * 64, tid);
      stage_tile64(Anxt + 8192, bsrc0 + (kw + 1) * 64, tid);
    }
    __builtin_amdgcn_s_setprio(1);
    #pragma unroll
    for (int ks = 0; ks < 2; ++ks){
      int ch8 = (((ks * 4 + qd) ^ (ln & 7)) * 8);   // swizzled read chunk
      short8 af[4], bfr[4];
      #pragma unroll
      for (int i = 0; i < 4; ++i)
        af[i] = *(const short8*)&Acur[(((wid & 1) * 4 + i) * 16 + ln) * 64 + ch8];
      #pragma unroll
      for (int j = 0; j < 4; ++j)
        bfr[j] = *(const short8*)&Bcur[(((wid >> 1) * 4 + j) * 16 + ln) * 64 + ch8];
      #pragma unroll
      for (int i = 0; i < 4; ++i)
        #pragma unroll
        for (int j = 0; j < 4; ++j)
          acc[i][j] = __builtin_amdgcn_mfma_f32_16x16x32_bf16(af[i], bfr[j], acc[i][j], 0, 0, 0);
    }
    __builtin_amdgcn_s_setprio(0);
    __syncthreads();   // drains this iter's stage (issued ~compute earlier);
                       // publishes buf[kw+1]; frees buf[kw] for next stage
  }
  // bias + pack into Dl[co][px] (pitch 136), then coalesced global stores
  float bias_[4][4];
  #pragma unroll
  for (int i = 0; i < 4; ++i){
    int co_l0 = ((wid & 1) * 4 + i) * 16 + qd * 4;
    #pragma unroll
    for (int r = 0; r < 4; ++r){
      int co_l = co_l0 + r;
      bias_[i][r] = (cot == 0) ? (co_l < 64 ? bq[co_l] : bk[co_l - 64])
                               : bv[(cot - 1) * 128 + co_l];
    }
  }
  #pragma unroll
  for (int i = 0; i < 4; ++i){
    int co_l0 = ((wid & 1) * 4 + i) * 16 + qd * 4;
    #pragma unroll
    for (int j = 0; j < 4; ++j){
      int pxl = ((wid >> 1) * 4 + j) * 16 + ln;
      #pragma unroll
      for (int r = 0; r < 4; ++r)
        Dl[(co_l0 + r) * 136 + pxl] = f2b(acc[i][j][r] + bias_[i][r]);
    }
  }
  __syncthreads();
  if (cot == 0){
    unsigned short* qb = qp + (size_t)(b * S + w) * S * C8;
    unsigned short* kb = kp + (size_t)(b * S + w) * S * C8;
    #pragma unroll
    for (int p = 0; p < 4; ++p){
      int idx = p * 256 + tid;          // 0..1023
      int cch = idx & 7, hh = idx >> 3;
      unsigned short tq[8] __attribute__((aligned(16)));
      unsigned short tk[8] __attribute__((aligned(16)));
      #pragma unroll
      for (int jj = 0; jj < 8; ++jj){
        tq[jj] = Dl[(cch * 8 + jj) * 136 + hh];
        tk[jj] = Dl[(64 + cch * 8 + jj) * 136 + hh];
      }
      *(uint4*)(qb + (size_t)hh * C8 + cch * 8) = *(uint4*)tq;
      *(uint4*)(kb + (size_t)hh * C8 + cch * 8) = *(uint4*)tk;
    }
  } else {
    unsigned short* vbb = vb + ((size_t)(b * C + (cot - 1) * 128) * S + w) * S;
    #pragma unroll
    for (int p = 0; p < 8; ++p){
      int idx = p * 256 + tid;          // 0..2047
      int c_l = idx >> 4, hc = (idx & 15) * 8;
      uint4 v = *(const uint4*)&Dl[c_l * 136 + hc];
      *(uint4*)(vbb + (size_t)c_l * SS + hc) = v;
    }
  }
}

// ---------------- K2: vb [b][c][w][h] -> vt [b][c][h][w] ----------------
__global__ __launch_bounds__(256) void k_tv(
    const unsigned short* __restrict__ vb, unsigned short* __restrict__ vt){
  __shared__ unsigned short T[128 * 130] __attribute__((aligned(16)));
  int bc = blockIdx.x;                  // b*C + c
  const unsigned short* src = vb + (size_t)bc * SS;
  unsigned short* dst = vt + (size_t)bc * SS;
  int tid = threadIdx.x;
  #pragma unroll
  for (int p = 0; p < 8; ++p){
    int idx = p * 256 + tid;            // 0..2047
    int wv = idx >> 4, ch = (idx & 15) * 8;
    uint4 v = *(const uint4*)(src + wv * S + ch);
    unsigned* d = (unsigned*)&T[wv * 130 + ch];
    d[0] = v.x; d[1] = v.y; d[2] = v.z; d[3] = v.w;
  }
  __syncthreads();
  #pragma unroll
  for (int p = 0; p < 8; ++p){
    int idx = p * 256 + tid;
    int h = idx >> 4, ch = (idx & 15) * 8;
    unsigned short tmp[8] __attribute__((aligned(16)));
    #pragma unroll
    for (int j = 0; j < 8; ++j) tmp[j] = T[(ch + j) * 130 + h];
    *(uint4*)(dst + h * S + ch) = *(uint4*)tmp;
  }
}

// ---------------- K3: column scores e_col[b][w][h][u] (masked diag), bf16 ---
__global__ __launch_bounds__(256) void k_ecol(
    const unsigned short* __restrict__ qp, const unsigned short* __restrict__ kp,
    unsigned short* __restrict__ eca){
  __shared__ unsigned short Aq[128 * 72] __attribute__((aligned(16)));
  __shared__ unsigned short Bk[128 * 72] __attribute__((aligned(16)));
  int blk = blockIdx.x; int h = blk & 127, b = blk >> 7;
  int tid = threadIdx.x, lane = tid & 63, wid = tid >> 6;
  int qd = lane >> 4, ln = lane & 15;
  #pragma unroll
  for (int p = 0; p < 4; ++p){
    int idx = p * 256 + tid;
    int row = idx >> 3, ch = (idx & 7) * 8;
    *(uint4*)&Aq[row * 72 + ch] = *(const uint4*)(qp + ((size_t)(b * S + row) * S + h) * C8 + ch);
    *(uint4*)&Bk[row * 72 + ch] = *(const uint4*)(kp + ((size_t)(b * S + row) * S + h) * C8 + ch);
  }
  __syncthreads();
  f32x4 acc[4][4];
  #pragma unroll
  for (int i = 0; i < 4; ++i)
    #pragma unroll
    for (int j = 0; j < 4; ++j) acc[i][j] = (f32x4){0.f, 0.f, 0.f, 0.f};
  #pragma unroll
  for (int ks = 0; ks < 2; ++ks){
    int ko = ks * 32 + qd * 8;
    short8 af[4], bfr[4];
    #pragma unroll
    for (int i = 0; i < 4; ++i)
      af[i] = *(const short8*)&Aq[(((wid & 1) * 4 + i) * 16 + ln) * 72 + ko];
    #pragma unroll
    for (int j = 0; j < 4; ++j)
      bfr[j] = *(const short8*)&Bk[(((wid >> 1) * 4 + j) * 16 + ln) * 72 + ko];
    #pragma unroll
    for (int i = 0; i < 4; ++i)
      #pragma unroll
      for (int j = 0; j < 4; ++j)
        acc[i][j] = __builtin_amdgcn_mfma_f32_16x16x32_bf16(af[i], bfr[j], acc[i][j], 0, 0, 0);
  }
  #pragma unroll
  for (int i = 0; i < 4; ++i){
    int w0 = ((wid & 1) * 4 + i) * 16 + qd * 4;
    #pragma unroll
    for (int j = 0; j < 4; ++j){
      int ug = ((wid >> 1) * 4 + j) * 16 + ln;
      #pragma unroll
      for (int r = 0; r < 4; ++r){
        int wg = w0 + r;
        float val = acc[i][j][r];
        if (wg == ug) val = NEG_BIG;
        eca[((size_t)(b * S + wg) * S + h) * S + ug] = f2b(val);
      }
    }
  }
}

// ------- K4: row scores + joint softmax; ac overwrites eca in place; ar out --
__global__ __launch_bounds__(256) void k_erow_softmax(
    const unsigned short* __restrict__ qp, const unsigned short* __restrict__ kp,
    unsigned short* __restrict__ eca, unsigned short* __restrict__ ar){
  __shared__ char sm[36864] __attribute__((aligned(16)));
  unsigned short* Aq = (unsigned short*)sm;              // [128][72]
  unsigned short* Bk = (unsigned short*)(sm + 18432);    // [128][72]
  unsigned short* El = (unsigned short*)sm;              // alias: [128][136] bf16
  float* redm = (float*)(sm + 34816);                    // [256]
  float* reds = (float*)(sm + 35840);                    // [256]
  int blk = blockIdx.x; int w = blk & 127, b = blk >> 7;
  int tid = threadIdx.x, lane = tid & 63, wid = tid >> 6;
  int qd = lane >> 4, ln = lane & 15;
  size_t tb = (size_t)(b * S + w) * SS;                  // tile base (elems)
  {
    const unsigned short* qsrc = qp + (size_t)(b * S + w) * S * C8;
    const unsigned short* ksrc = kp + (size_t)(b * S + w) * S * C8;
    #pragma unroll
    for (int p = 0; p < 4; ++p){
      int idx = p * 256 + tid;
      int row = idx >> 3, ch = (idx & 7) * 8;
      *(uint4*)&Aq[row * 72 + ch] = *(const uint4*)(qsrc + row * C8 + ch);
      *(uint4*)&Bk[row * 72 + ch] = *(const uint4*)(ksrc + row * C8 + ch);
    }
  }
  __syncthreads();
  f32x4 acc[4][4];
  #pragma unroll
  for (int i = 0; i < 4; ++i)
    #pragma unroll
    for (int j = 0; j < 4; ++j) acc[i][j] = (f32x4){0.f, 0.f, 0.f, 0.f};
  #pragma unroll
  for (int ks = 0; ks < 2; ++ks){
    int ko = ks * 32 + qd * 8;
    short8 af[4], bfr[4];
    #pragma unroll
    for (int i = 0; i < 4; ++i)
      af[i] = *(const short8*)&Aq[(((wid & 1) * 4 + i) * 16 + ln) * 72 + ko];
    #pragma unroll
    for (int j = 0; j < 4; ++j)
      bfr[j] = *(const short8*)&Bk[(((wid >> 1) * 4 + j) * 16 + ln) * 72 + ko];
    #pragma unroll
    for (int i = 0; i < 4; ++i)
      #pragma unroll
      for (int j = 0; j < 4; ++j)
        acc[i][j] = __builtin_amdgcn_mfma_f32_16x16x32_bf16(af[i], bfr[j], acc[i][j], 0, 0, 0);
  }
  __syncthreads();     // done with Aq/Bk; El may now alias them
  #pragma unroll
  for (int i = 0; i < 4; ++i){
    int h0 = ((wid & 1) * 4 + i) * 16 + qd * 4;
    #pragma unroll
    for (int j = 0; j < 4; ++j){
      int ul = ((wid >> 1) * 4 + j) * 16 + ln;
      #pragma unroll
      for (int r = 0; r < 4; ++r)
        El[(h0 + r) * 136 + ul] = f2b(acc[i][j][r]);
    }
  }
  __syncthreads();
  // softmax over 256 = [col(128 from eca) | row(128 from El)] per h
  int h = tid >> 1, half = tid & 1;
  const uint4* src4 = (half == 0) ? (const uint4*)(eca + tb + (size_t)h * S)
                                  : (const uint4*)&El[h * 136];
  float mx = -3.0e38f;
  #pragma unroll 4
  for (int u = 0; u < 16; ++u){
    uint4 v = src4[u];
    const unsigned short* e = (const unsigned short*)&v;
    #pragma unroll
    for (int jj = 0; jj < 8; ++jj) mx = fmaxf(mx, b2f(e[jj]));
  }
  redm[tid] = mx;
  __syncthreads();
  float m = fmaxf(mx, redm[tid ^ 1]);
  float s = 0.f;
  #pragma unroll 4
  for (int u = 0; u < 16; ++u){
    uint4 v = src4[u];
    const unsigned short* e = (const unsigned short*)&v;
    #pragma unroll
    for (int jj = 0; jj < 8; ++jj) s += __expf(b2f(e[jj]) - m);
  }
  reds[tid] = s;
  __syncthreads();
  float inv = 1.0f / (s + reds[tid ^ 1]);
  uint4* dst4 = (half == 0) ? (uint4*)(eca + tb + (size_t)h * S)
                            : (uint4*)(ar + tb + (size_t)h * S);
  #pragma unroll 4
  for (int u = 0; u < 16; ++u){
    uint4 v = src4[u];
    const unsigned short* e = (const unsigned short*)&v;
    unsigned short o[8] __attribute__((aligned(16)));
    #pragma unroll
    for (int jj = 0; jj < 8; ++jj) o[jj] = f2b(__expf(b2f(e[jj]) - m) * inv);
    dst4[u] = *(uint4*)o;
  }
}

// ------- K5: out_row GEMM -> orw[b][c][w][h] bf16 (raw acc, no gamma/x) ------
__global__ __launch_bounds__(256) void k_outrow(
    const unsigned short* __restrict__ vb, const unsigned short* __restrict__ ar,
    unsigned short* __restrict__ orw){
  __shared__ unsigned short Av[128 * 72] __attribute__((aligned(16)));
  __shared__ unsigned short Ba[128 * 72] __attribute__((aligned(16)));
  int blk = blockIdx.x;                 // ((b*128+w)*4 + ct)
  int ct = blk & 3; int bw = blk >> 2;
  int w = bw & 127, b = bw >> 7;
  int tid = threadIdx.x, lane = tid & 63, wid = tid >> 6;
  int qd = lane >> 4, ln = lane & 15;
  size_t tb = (size_t)(b * S + w) * SS;
  f32x4 acc[4][4];
  #pragma unroll
  for (int i = 0; i < 4; ++i)
    #pragma unroll
    for (int j = 0; j < 4; ++j) acc[i][j] = (f32x4){0.f, 0.f, 0.f, 0.f};
  for (int kw = 0; kw < 2; ++kw){
    __syncthreads();
    #pragma unroll
    for (int p = 0; p < 4; ++p){
      int idx = p * 256 + tid;
      int row = idx >> 3, ch = (idx & 7) * 8;
      *(uint4*)&Av[row * 72 + ch] =
        *(const uint4*)(vb + ((size_t)(b * C + ct * 128 + row) * S + w) * S + kw * 64 + ch);
      *(uint4*)&Ba[row * 72 + ch] =
        *(const uint4*)(ar + tb + (size_t)row * S + kw * 64 + ch);
    }
    __syncthreads();
    #pragma unroll
    for (int ks = 0; ks < 2; ++ks){
      int ko = ks * 32 + qd * 8;
      short8 af[4], bfr[4];
      #pragma unroll
      for (int i = 0; i < 4; ++i)
        af[i] = *(const short8*)&Av[(((wid & 1) * 4 + i) * 16 + ln) * 72 + ko];
      #pragma unroll
      for (int j = 0; j < 4; ++j)
        bfr[j] = *(const short8*)&Ba[(((wid >> 1) * 4 + j) * 16 + ln) * 72 + ko];
      #pragma unroll
      for (int i = 0; i < 4; ++i)
        #pragma unroll
        for (int j = 0; j < 4; ++j)
          acc[i][j] = __builtin_amdgcn_mfma_f32_16x16x32_bf16(af[i], bfr[j], acc[i][j], 0, 0, 0);
    }
  }
  #pragma unroll
  for (int i = 0; i < 4; ++i){
    int c0 = ((wid & 1) * 4 + i) * 16 + qd * 4;
    #pragma unroll
    for (int j = 0; j < 4; ++j){
      int hl = ((wid >> 1) * 4 + j) * 16 + ln;
      #pragma unroll
      for (int r = 0; r < 4; ++r){
        int cg = ct * 128 + c0 + r;
        orw[((size_t)(b * C + cg) * S + w) * S + hl] = f2b(acc[i][j][r]);
      }
    }
  }
}

// ------- K6: out_col -> oct[b][h][c][w] bf16 ----------------
__global__ __launch_bounds__(256) void k_outcol(
    const unsigned short* __restrict__ vt, const unsigned short* __restrict__ eca,
    unsigned short* __restrict__ oct){
  __shared__ unsigned short Av[128 * 72] __attribute__((aligned(16)));
  __shared__ unsigned short Ba[128 * 72] __attribute__((aligned(16)));
  int blk = blockIdx.x;                 // ((b*128+h)*4 + ct)
  int ct = blk & 3; int bh = blk >> 2;
  int h = bh & 127, b = bh >> 7;
  int tid = threadIdx.x, lane = tid & 63, wid = tid >> 6;
  int qd = lane >> 4, ln = lane & 15;
  f32x4 acc[4][4];
  #pragma unroll
  for (int i = 0; i < 4; ++i)
    #pragma unroll
    for (int j = 0; j < 4; ++j) acc[i][j] = (f32x4){0.f, 0.f, 0.f, 0.f};
  for (int kw = 0; kw < 2; ++kw){
    __syncthreads();
    #pragma unroll
    for (int p = 0; p < 4; ++p){
      int idx = p * 256 + tid;
      int row = idx >> 3, ch = (idx & 7) * 8;
      *(uint4*)&Av[row * 72 + ch] =
        *(const uint4*)(vt + ((size_t)(b * C + ct * 128 + row) * S + h) * S + kw * 64 + ch);
      *(uint4*)&Ba[row * 72 + ch] =
        *(const uint4*)(eca + ((size_t)(b * S + row) * S + h) * S + kw * 64 + ch);
    }
    __syncthreads();
    #pragma unroll
    for (int ks = 0; ks < 2; ++ks){
      int ko = ks * 32 + qd * 8;
      short8 af[4], bfr[4];
      #pragma unroll
      for (int i = 0; i < 4; ++i)
        af[i] = *(const short8*)&Av[(((wid & 1) * 4 + i) * 16 + ln) * 72 + ko];
      #pragma unroll
      for (int j = 0; j < 4; ++j)
        bfr[j] = *(const short8*)&Ba[(((wid >> 1) * 4 + j) * 16 + ln) * 72 + ko];
      #pragma unroll
      for (int i = 0; i < 4; ++i)
        #pragma unroll
        for (int j = 0; j < 4; ++j)
          acc[i][j] = __builtin_amdgcn_mfma_f32_16x16x32_bf16(af[i], bfr[j], acc[i][j], 0, 0, 0);
    }
  }
  #pragma unroll
  for (int i = 0; i < 4; ++i){
    int c0 = ((wid & 1) * 4 + i) * 16 + qd * 4;
    #pragma unroll
    for (int j = 0; j < 4; ++j){
      int wl = ((wid >> 1) * 4 + j) * 16 + ln;
      #pragma unroll
      for (int r = 0; r < 4; ++r){
        int cg = ct * 128 + c0 + r;
        oct[((size_t)(b * S + h) * C + cg) * S + wl] = f2b(acc[i][j][r]);
      }
    }
  }
}

// ------- K7: out = gamma * (orw + transpose(oct)) + x  (single out write) ----
__global__ __launch_bounds__(256) void k_final(
    const unsigned short* __restrict__ oct, const unsigned short* __restrict__ orw,
    const float* __restrict__ x, const float* __restrict__ gamma,
    float* __restrict__ out){
  __shared__ unsigned short T[128 * 130] __attribute__((aligned(16)));
  int blk = blockIdx.x;                 // b*C + c
  int c = blk & 511, b = blk >> 9;
  int tid = threadIdx.x;
  float g = gamma[0];
  #pragma unroll
  for (int p = 0; p < 8; ++p){
    int idx = p * 256 + tid;
    int hh = idx >> 4, ch = (idx & 15) * 8;
    uint4 v = *(const uint4*)(oct + ((size_t)(b * S + hh) * C + c) * S + ch);
    unsigned* d = (unsigned*)&T[hh * 130 + ch];
    d[0] = v.x; d[1] = v.y; d[2] = v.z; d[3] = v.w;
  }
  __syncthreads();
  #pragma unroll
  for (int p = 0; p < 8; ++p){
    int idx = p * 256 + tid;
    int wv = idx >> 4, hch = (idx & 15) * 8;
    size_t o = ((size_t)(b * C + c) * S + wv) * S + hch;
    uint4 rv = *(const uint4*)(orw + o);
    const unsigned short* rr = (const unsigned short*)&rv;
    float4 x0 = *(const float4*)(x + o);
    float4 x1 = *(const float4*)(x + o + 4);
    float4 o0, o1;
    o0.x = g * (b2f(rr[0]) + b2f(T[(hch + 0) * 130 + wv])) + x0.x;
    o0.y = g * (b2f(rr[1]) + b2f(T[(hch + 1) * 130 + wv])) + x0.y;
    o0.z = g * (b2f(rr[2]) + b2f(T[(hch + 2) * 130 + wv])) + x0.z;
    o0.w = g * (b2f(rr[3]) + b2f(T[(hch + 3) * 130 + wv])) + x0.w;
    o1.x = g * (b2f(rr[4]) + b2f(T[(hch + 4) * 130 + wv])) + x1.x;
    o1.y = g * (b2f(rr[5]) + b2f(T[(hch + 5) * 130 + wv])) + x1.y;
    o1.z = g * (b2f(rr[6]) + b2f(T[(hch + 6) * 130 + wv])) + x1.z;
    o1.w = g * (b2f(rr[7]) + b2f(T[(hch + 7) * 130 + wv])) + x1.w;
    *(float4*)(out + o) = o0;
    *(float4*)(out + o + 4) = o1;
  }
}

extern "C" void kernel_launch(void* const* d_in, const int* in_sizes, int n_in,
                              void* d_out, int out_size, void* d_ws, size_t ws_size,
                              hipStream_t stream){
  const float* x     = (const float*)d_in[0];
  const float* Wq    = (const float*)d_in[1];
  const float* bq    = (const float*)d_in[2];
  const float* Wk    = (const float*)d_in[3];
  const float* bk    = (const float*)d_in[4];
  const float* Wv    = (const float*)d_in[5];
  const float* bv    = (const float*)d_in[6];
  const float* gamma = (const float*)d_in[7];
  float* out = (float*)d_out;
  char* ws = (char*)d_ws;

  const size_t OFF_WALL = 0;
  const size_t OFF_XP   = 1ull << 20;                    // 134,217,728
  const size_t OFF_QP   = OFF_XP  + 134217728ull;        // 16,777,216
  const size_t OFF_KP   = OFF_QP  + 16777216ull;         // 16,777,216
  const size_t OFF_VB   = OFF_KP  + 16777216ull;         // 134,217,728
  const size_t OFF_VT   = OFF_VB  + 134217728ull;        // 134,217,728
  const size_t OFF_ECA  = OFF_VT  + 134217728ull;        // 33,554,432
  const size_t OFF_AR   = OFF_ECA + 33554432ull;         // 33,554,432
  const size_t OFF_OCT  = OFF_XP;                        // alias: xp dead after k_qkv
  const size_t OFF_ORW  = OFF_VT;                        // alias: vt dead after k_outcol
  const size_t NEED     = OFF_AR + 33554432ull;          // ~481 MiB
  if (ws_size < NEED) return;                            // cannot run; fail cleanly

  unsigned short* wall = (unsigned short*)(ws + OFF_WALL);
  unsigned short* xp   = (unsigned short*)(ws + OFF_XP);
  unsigned short* qp   = (unsigned short*)(ws + OFF_QP);
  unsigned short* kp   = (unsigned short*)(ws + OFF_KP);
  unsigned short* vb   = (unsigned short*)(ws + OFF_VB);
  unsigned short* vt   = (unsigned short*)(ws + OFF_VT);
  unsigned short* eca  = (unsigned short*)(ws + OFF_ECA);
  unsigned short* ar   = (unsigned short*)(ws + OFF_AR);
  unsigned short* oct  = (unsigned short*)(ws + OFF_OCT);
  unsigned short* orw  = (unsigned short*)(ws + OFF_ORW);

  k_pack_w      <<<1280, 256, 0, stream>>>(Wq, Wk, Wv, wall);
  k_xp          <<<4096, 256, 0, stream>>>(x, xp);
  k_qkv         <<<5120, 256, 0, stream>>>(xp, wall, bq, bk, bv, qp, kp, vb);
  k_tv          <<<4096, 256, 0, stream>>>(vb, vt);
  k_ecol        <<<1024, 256, 0, stream>>>(qp, kp, eca);
  k_erow_softmax<<<1024, 256, 0, stream>>>(qp, kp, eca, ar);
  k_outcol      <<<4096, 256, 0, stream>>>(vt, eca, oct);      // before k_outrow: orw aliases vt
  k_outrow      <<<4096, 256, 0, stream>>>(vb, ar, orw);
  k_final       <<<4096, 256, 0, stream>>>(oct, orw, x, gamma, out);
}

// Round 3
// 921.226 us; speedup vs baseline: 1.1932x; 1.0720x over previous
//
#include <hip/hip_runtime.h>
#include <hip/hip_bf16.h>

// Criss-Cross Attention, MI355X. Round 5:
//  - fuse k_erow_softmax + k_outrow -> k_erow_sm_outrow: ar lives in LDS
//    (in-place normalize of El), PV GEMM staged via swizzled global_load_lds;
//    orw aliases vb IN PLACE (block (b,w) reads/writes only column w).
//  - k_xp / k_tv / k_final: PR(r)=((r&7)<<4)|(r>>3) row permutation in the
//    LDS transpose tile -> column-gather reads go 8-way-conflict -> free.
//  - k_qkv unchanged from R4 (2-phase dbuf prefetch + T2 swizzle + setprio).
// B=8, C=512, C8=64, S=128. All MFMA = 16x16x32 bf16 (verified layouts):
//   a/b frag: M[row = lane&15][k = (lane>>4)*8 + j], D = A * B^T
//   D frag:   D[row = (lane>>4)*4 + reg][col = lane&15]

#define S 128
#define SS 16384
#define C 512
#define C8 64
#define NEG_BIG -1000000000.0f

using short8 = __attribute__((ext_vector_type(8))) short;
using f32x4  = __attribute__((ext_vector_type(4))) float;

#define GPTR(p) ((const __attribute__((address_space(1))) void*)(p))
#define LPTR(p) ((__attribute__((address_space(3))) void*)(p))

// row permutation for 128-row LDS transpose tiles (bijective on 0..127)
#define PR(r) ((((r) & 7) << 4) | ((r) >> 3))

__device__ __forceinline__ unsigned short f2b(float f){
  union { float f; unsigned u; } v; v.f = f;
  unsigned r = (v.u + 0x7fffu + ((v.u >> 16) & 1u)) >> 16;
  return (unsigned short)r;
}
__device__ __forceinline__ float b2f(unsigned short h){
  union { unsigned u; float f; } v; v.u = ((unsigned)h) << 16;
  return v.f;
}

// stage one [128][64] bf16 tile (row stride = rstride elems) into LDS,
// chunk-swizzled: LDS chunk gi (16B) receives global chunk (gi&7)^(row&7).
// dest is linear (wave-uniform base + lane*16) as global_load_lds requires.
__device__ __forceinline__ void stage_tile64(unsigned short* dst,
    const unsigned short* src, size_t rstride, int tid){
  #pragma unroll
  for (int p = 0; p < 4; ++p){
    int gi = p * 256 + tid;             // 0..1023
    int row = gi >> 3, cc = gi & 7;
    int kc = (cc ^ (row & 7)) * 8;      // inverse-swizzled global chunk
    __builtin_amdgcn_global_load_lds(GPTR(src + (size_t)row * rstride + kc),
                                     LPTR((char*)dst + gi * 16), 16, 0, 0);
  }
}

// ---------------- K0a: pack Wq|Wk|Wv -> wall[640][512] bf16 ----------------
__global__ __launch_bounds__(256) void k_pack_w(
    const float* __restrict__ Wq, const float* __restrict__ Wk,
    const float* __restrict__ Wv, unsigned short* __restrict__ wall){
  int i = blockIdx.x * 256 + threadIdx.x;
  if (i >= 640 * C) return;
  int co = i >> 9, ci = i & (C - 1);
  float v;
  if (co < 64)        v = Wq[co * C + ci];
  else if (co < 128)  v = Wk[(co - 64) * C + ci];
  else                v = Wv[(co - 128) * C + ci];
  wall[i] = f2b(v);
}

// ---------------- K0b: x (f32, [b][ci][w][h]) -> xp (bf16, [b][w][h][ci]) ----
__global__ __launch_bounds__(256) void k_xp(
    const float* __restrict__ x, unsigned short* __restrict__ xp){
  __shared__ unsigned short T[128 * 130] __attribute__((aligned(16)));
  int blk = blockIdx.x;                 // ((b*128 + w)*4 + ct)
  int ct = blk & 3; int bw = blk >> 2;
  int w = bw & 127; int b = bw >> 7;
  int tid = threadIdx.x;
  int ci0 = ct * 128;
  const float* xb = x + ((size_t)(b * C + ci0) * S + w) * S;  // + cc*SS + h
  #pragma unroll
  for (int p = 0; p < 16; ++p){
    int idx = p * 256 + tid;            // 0..4095
    int cc = idx >> 5;
    int h4 = (idx & 31) * 4;
    float4 v = *(const float4*)(xb + (size_t)cc * SS + h4);
    unsigned* d = (unsigned*)&T[PR(cc) * 130 + h4];
    d[0] = (unsigned)f2b(v.x) | ((unsigned)f2b(v.y) << 16);
    d[1] = (unsigned)f2b(v.z) | ((unsigned)f2b(v.w) << 16);
  }
  __syncthreads();
  unsigned short* xpb = xp + (size_t)(b * S + w) * S * C + ci0;
  #pragma unroll
  for (int p = 0; p < 8; ++p){
    int idx = p * 256 + tid;            // 0..2047
    int h  = idx >> 4;
    int ch = (idx & 15) * 8;            // cc chunk
    unsigned short tmp[8] __attribute__((aligned(16)));
    #pragma unroll
    for (int j = 0; j < 8; ++j) tmp[j] = T[PR(ch + j) * 130 + h];
    *(uint4*)(xpb + (size_t)h * C + ch) = *(uint4*)tmp;
  }
}

// ---------------- K1: qkv projection GEMM (2-phase dbuf prefetch) ----------
// Swizzled grid (5120): pxsub=blk&7, t=blk>>3, cot=t%5, pxg=t/5, px=pxg*8+pxsub
// -> the 5 cot-blocks of one px-tile are temporally adjacent + same XCD.
__global__ __launch_bounds__(256) void k_qkv(
    const unsigned short* __restrict__ xp, const unsigned short* __restrict__ wall,
    const float* __restrict__ bq, const float* __restrict__ bk,
    const float* __restrict__ bv,
    unsigned short* __restrict__ qp, unsigned short* __restrict__ kp,
    unsigned short* __restrict__ vb){
  __shared__ unsigned short sm[32768] __attribute__((aligned(16)));  // 65536 B
  // buf k (k=0,1): A at sm + k*16384, B at sm + k*16384 + 8192 (each [128][64])
  unsigned short* Dl = sm;              // alias: [128][136] (17408 shorts)
  int blk = blockIdx.x;
  int pxsub = blk & 7; int t = blk >> 3;
  int cot = t % 5; int pxg = t / 5;
  int pxt = pxg * 8 + pxsub;            // 0..1023
  int w = pxt & 127, b = pxt >> 7;
  int tid = threadIdx.x, lane = tid & 63, wid = tid >> 6;
  int qd = lane >> 4, ln = lane & 15;
  const unsigned short* asrc0 = wall + (size_t)cot * 128 * C;
  const unsigned short* bsrc0 = xp + (size_t)pxt * 128 * C;
  f32x4 acc[4][4];
  #pragma unroll
  for (int i = 0; i < 4; ++i)
    #pragma unroll
    for (int j = 0; j < 4; ++j) acc[i][j] = (f32x4){0.f, 0.f, 0.f, 0.f};

  // prologue: stage kw=0 into buf0
  stage_tile64(sm,        asrc0, C, tid);
  stage_tile64(sm + 8192, bsrc0, C, tid);
  __syncthreads();                      // drains vmcnt -> buf0 published

  for (int kw = 0; kw < 8; ++kw){
    unsigned short* Acur = sm + (kw & 1) * 16384;
    unsigned short* Bcur = Acur + 8192;
    if (kw < 7){                        // issue next-tile stage BEFORE compute
      unsigned short* Anxt = sm + ((kw + 1) & 1) * 16384;
      stage_tile64(Anxt,        asrc0 + (kw + 1) * 64, C, tid);
      stage_tile64(Anxt + 8192, bsrc0 + (kw + 1) * 64, C, tid);
    }
    __builtin_amdgcn_s_setprio(1);
    #pragma unroll
    for (int ks = 0; ks < 2; ++ks){
      int ch8 = (((ks * 4 + qd) ^ (ln & 7)) * 8);   // swizzled read chunk
      short8 af[4], bfr[4];
      #pragma unroll
      for (int i = 0; i < 4; ++i)
        af[i] = *(const short8*)&Acur[(((wid & 1) * 4 + i) * 16 + ln) * 64 + ch8];
      #pragma unroll
      for (int j = 0; j < 4; ++j)
        bfr[j] = *(const short8*)&Bcur[(((wid >> 1) * 4 + j) * 16 + ln) * 64 + ch8];
      #pragma unroll
      for (int i = 0; i < 4; ++i)
        #pragma unroll
        for (int j = 0; j < 4; ++j)
          acc[i][j] = __builtin_amdgcn_mfma_f32_16x16x32_bf16(af[i], bfr[j], acc[i][j], 0, 0, 0);
    }
    __builtin_amdgcn_s_setprio(0);
    __syncthreads();   // drains this iter's stage (issued ~compute earlier);
                       // publishes buf[kw+1]; frees buf[kw] for next stage
  }
  // bias + pack into Dl[co][px] (pitch 136), then coalesced global stores
  float bias_[4][4];
  #pragma unroll
  for (int i = 0; i < 4; ++i){
    int co_l0 = ((wid & 1) * 4 + i) * 16 + qd * 4;
    #pragma unroll
    for (int r = 0; r < 4; ++r){
      int co_l = co_l0 + r;
      bias_[i][r] = (cot == 0) ? (co_l < 64 ? bq[co_l] : bk[co_l - 64])
                               : bv[(cot - 1) * 128 + co_l];
    }
  }
  #pragma unroll
  for (int i = 0; i < 4; ++i){
    int co_l0 = ((wid & 1) * 4 + i) * 16 + qd * 4;
    #pragma unroll
    for (int j = 0; j < 4; ++j){
      int pxl = ((wid >> 1) * 4 + j) * 16 + ln;
      #pragma unroll
      for (int r = 0; r < 4; ++r)
        Dl[(co_l0 + r) * 136 + pxl] = f2b(acc[i][j][r] + bias_[i][r]);
    }
  }
  __syncthreads();
  if (cot == 0){
    unsigned short* qb = qp + (size_t)(b * S + w) * S * C8;
    unsigned short* kb = kp + (size_t)(b * S + w) * S * C8;
    #pragma unroll
    for (int p = 0; p < 4; ++p){
      int idx = p * 256 + tid;          // 0..1023
      int cch = idx & 7, hh = idx >> 3;
      unsigned short tq[8] __attribute__((aligned(16)));
      unsigned short tk[8] __attribute__((aligned(16)));
      #pragma unroll
      for (int jj = 0; jj < 8; ++jj){
        tq[jj] = Dl[(cch * 8 + jj) * 136 + hh];
        tk[jj] = Dl[(64 + cch * 8 + jj) * 136 + hh];
      }
      *(uint4*)(qb + (size_t)hh * C8 + cch * 8) = *(uint4*)tq;
      *(uint4*)(kb + (size_t)hh * C8 + cch * 8) = *(uint4*)tk;
    }
  } else {
    unsigned short* vbb = vb + ((size_t)(b * C + (cot - 1) * 128) * S + w) * S;
    #pragma unroll
    for (int p = 0; p < 8; ++p){
      int idx = p * 256 + tid;          // 0..2047
      int c_l = idx >> 4, hc = (idx & 15) * 8;
      uint4 v = *(const uint4*)&Dl[c_l * 136 + hc];
      *(uint4*)(vbb + (size_t)c_l * SS + hc) = v;
    }
  }
}

// ---------------- K2: vb [b][c][w][h] -> vt [b][c][h][w] ----------------
__global__ __launch_bounds__(256) void k_tv(
    const unsigned short* __restrict__ vb, unsigned short* __restrict__ vt){
  __shared__ unsigned short T[128 * 130] __attribute__((aligned(16)));
  int bc = blockIdx.x;                  // b*C + c
  const unsigned short* src = vb + (size_t)bc * SS;
  unsigned short* dst = vt + (size_t)bc * SS;
  int tid = threadIdx.x;
  #pragma unroll
  for (int p = 0; p < 8; ++p){
    int idx = p * 256 + tid;            // 0..2047
    int wv = idx >> 4, ch = (idx & 15) * 8;
    uint4 v = *(const uint4*)(src + wv * S + ch);
    unsigned* d = (unsigned*)&T[PR(wv) * 130 + ch];
    d[0] = v.x; d[1] = v.y; d[2] = v.z; d[3] = v.w;
  }
  __syncthreads();
  #pragma unroll
  for (int p = 0; p < 8; ++p){
    int idx = p * 256 + tid;
    int h = idx >> 4, ch = (idx & 15) * 8;
    unsigned short tmp[8] __attribute__((aligned(16)));
    #pragma unroll
    for (int j = 0; j < 8; ++j) tmp[j] = T[PR(ch + j) * 130 + h];
    *(uint4*)(dst + h * S + ch) = *(uint4*)tmp;
  }
}

// ---------------- K3: column scores e_col[b][w][h][u] (masked diag), bf16 ---
__global__ __launch_bounds__(256) void k_ecol(
    const unsigned short* __restrict__ qp, const unsigned short* __restrict__ kp,
    unsigned short* __restrict__ eca){
  __shared__ unsigned short Aq[128 * 72] __attribute__((aligned(16)));
  __shared__ unsigned short Bk[128 * 72] __attribute__((aligned(16)));
  int blk = blockIdx.x; int h = blk & 127, b = blk >> 7;
  int tid = threadIdx.x, lane = tid & 63, wid = tid >> 6;
  int qd = lane >> 4, ln = lane & 15;
  #pragma unroll
  for (int p = 0; p < 4; ++p){
    int idx = p * 256 + tid;
    int row = idx >> 3, ch = (idx & 7) * 8;
    *(uint4*)&Aq[row * 72 + ch] = *(const uint4*)(qp + ((size_t)(b * S + row) * S + h) * C8 + ch);
    *(uint4*)&Bk[row * 72 + ch] = *(const uint4*)(kp + ((size_t)(b * S + row) * S + h) * C8 + ch);
  }
  __syncthreads();
  f32x4 acc[4][4];
  #pragma unroll
  for (int i = 0; i < 4; ++i)
    #pragma unroll
    for (int j = 0; j < 4; ++j) acc[i][j] = (f32x4){0.f, 0.f, 0.f, 0.f};
  #pragma unroll
  for (int ks = 0; ks < 2; ++ks){
    int ko = ks * 32 + qd * 8;
    short8 af[4], bfr[4];
    #pragma unroll
    for (int i = 0; i < 4; ++i)
      af[i] = *(const short8*)&Aq[(((wid & 1) * 4 + i) * 16 + ln) * 72 + ko];
    #pragma unroll
    for (int j = 0; j < 4; ++j)
      bfr[j] = *(const short8*)&Bk[(((wid >> 1) * 4 + j) * 16 + ln) * 72 + ko];
    #pragma unroll
    for (int i = 0; i < 4; ++i)
      #pragma unroll
      for (int j = 0; j < 4; ++j)
        acc[i][j] = __builtin_amdgcn_mfma_f32_16x16x32_bf16(af[i], bfr[j], acc[i][j], 0, 0, 0);
  }
  #pragma unroll
  for (int i = 0; i < 4; ++i){
    int w0 = ((wid & 1) * 4 + i) * 16 + qd * 4;
    #pragma unroll
    for (int j = 0; j < 4; ++j){
      int ug = ((wid >> 1) * 4 + j) * 16 + ln;
      #pragma unroll
      for (int r = 0; r < 4; ++r){
        int wg = w0 + r;
        float val = acc[i][j][r];
        if (wg == ug) val = NEG_BIG;
        eca[((size_t)(b * S + wg) * S + h) * S + ug] = f2b(val);
      }
    }
  }
}

// ------- K4: row scores + joint softmax + out_row PV GEMM (fused) -----------
// Per (b,w): e_row via MFMA -> El; joint softmax over [eca | El]; ac -> eca
// (in place, for k_outcol), ar normalized IN PLACE into El (LDS only);
// then out_row = ar @ v_row staged from vb; result OVERWRITES vb in place
// (block (b,w) reads and writes only vb[b][:][w][:]; per-ct read-then-write).
__global__ __launch_bounds__(256) void k_erow_sm_outrow(
    const unsigned short* __restrict__ qp, const unsigned short* __restrict__ kp,
    unsigned short* __restrict__ eca, unsigned short* vb){
  __shared__ char sm[71680] __attribute__((aligned(16)));
  unsigned short* Aq  = (unsigned short*)sm;             // [128][72] (phase 1)
  unsigned short* Bk  = (unsigned short*)(sm + 18432);   // [128][72] (phase 1)
  unsigned short* El  = (unsigned short*)sm;             // alias: [128][136]
  unsigned short* Av0 = (unsigned short*)(sm + 36864);   // [128][64] swizzled
  unsigned short* Av1 = (unsigned short*)(sm + 53248);   // [128][64] swizzled
  float* redm = (float*)(sm + 69632);                    // [256]
  float* reds = (float*)(sm + 70656);                    // [256]
  int blk = blockIdx.x; int w = blk & 127, b = blk >> 7;
  int tid = threadIdx.x, lane = tid & 63, wid = tid >> 6;
  int qd = lane >> 4, ln = lane & 15;
  size_t tb = (size_t)(b * S + w) * SS;                  // eca tile base (elems)
  const unsigned short* vsrc0 = vb + (size_t)(b * C) * SS + (size_t)w * S;

  // ---- phase 1: stage q/k, plus prefetch first V tile into Av0 ----
  {
    const unsigned short* qsrc = qp + (size_t)(b * S + w) * S * C8;
    const unsigned short* ksrc = kp + (size_t)(b * S + w) * S * C8;
    #pragma unroll
    for (int p = 0; p < 4; ++p){
      int idx = p * 256 + tid;
      int row = idx >> 3, ch = (idx & 7) * 8;
      *(uint4*)&Aq[row * 72 + ch] = *(const uint4*)(qsrc + row * C8 + ch);
      *(uint4*)&Bk[row * 72 + ch] = *(const uint4*)(ksrc + row * C8 + ch);
    }
  }
  stage_tile64(Av0, vsrc0, SS, tid);    // s=0 (ct=0, kw=0), hides under phase 1
  __syncthreads();
  f32x4 acc[4][4];
  #pragma unroll
  for (int i = 0; i < 4; ++i)
    #pragma unroll
    for (int j = 0; j < 4; ++j) acc[i][j] = (f32x4){0.f, 0.f, 0.f, 0.f};
  #pragma unroll
  for (int ks = 0; ks < 2; ++ks){
    int ko = ks * 32 + qd * 8;
    short8 af[4], bfr[4];
    #pragma unroll
    for (int i = 0; i < 4; ++i)
      af[i] = *(const short8*)&Aq[(((wid & 1) * 4 + i) * 16 + ln) * 72 + ko];
    #pragma unroll
    for (int j = 0; j < 4; ++j)
      bfr[j] = *(const short8*)&Bk[(((wid >> 1) * 4 + j) * 16 + ln) * 72 + ko];
    #pragma unroll
    for (int i = 0; i < 4; ++i)
      #pragma unroll
      for (int j = 0; j < 4; ++j)
        acc[i][j] = __builtin_amdgcn_mfma_f32_16x16x32_bf16(af[i], bfr[j], acc[i][j], 0, 0, 0);
  }
  __syncthreads();     // done with Aq/Bk; El may now alias them
  #pragma unroll
  for (int i = 0; i < 4; ++i){
    int h0 = ((wid & 1) * 4 + i) * 16 + qd * 4;
    #pragma unroll
    for (int j = 0; j < 4; ++j){
      int ul = ((wid >> 1) * 4 + j) * 16 + ln;
      #pragma unroll
      for (int r = 0; r < 4; ++r)
        El[(h0 + r) * 136 + ul] = f2b(acc[i][j][r]);
    }
  }
  __syncthreads();
  // ---- joint softmax over 256 = [col(eca) | row(El)] per h; 2 thr per h ----
  {
    int h = tid >> 1, half = tid & 1;
    const uint4* src4 = (half == 0) ? (const uint4*)(eca + tb + (size_t)h * S)
                                    : (const uint4*)&El[h * 136];
    float mx = -3.0e38f;
    #pragma unroll 4
    for (int u = 0; u < 16; ++u){
      uint4 v = src4[u];
      const unsigned short* e = (const unsigned short*)&v;
      #pragma unroll
      for (int jj = 0; jj < 8; ++jj) mx = fmaxf(mx, b2f(e[jj]));
    }
    redm[tid] = mx;
    __syncthreads();
    float m = fmaxf(mx, redm[tid ^ 1]);
    float s = 0.f;
    #pragma unroll 4
    for (int u = 0; u < 16; ++u){
      uint4 v = src4[u];
      const unsigned short* e = (const unsigned short*)&v;
      #pragma unroll
      for (int jj = 0; jj < 8; ++jj) s += __expf(b2f(e[jj]) - m);
    }
    reds[tid] = s;
    __syncthreads();
    float inv = 1.0f / (s + reds[tid ^ 1]);
    uint4* dst4 = (half == 0) ? (uint4*)(eca + tb + (size_t)h * S)
                              : (uint4*)&El[h * 136];       // ar in place
    #pragma unroll 4
    for (int u = 0; u < 16; ++u){
      uint4 v = src4[u];
      const unsigned short* e = (const unsigned short*)&v;
      unsigned short o[8] __attribute__((aligned(16)));
      #pragma unroll
      for (int jj = 0; jj < 8; ++jj) o[jj] = f2b(__expf(b2f(e[jj]) - m) * inv);
      dst4[u] = *(uint4*)o;
    }
  }
  __syncthreads();      // El now holds normalized ar[128 h][128 u]

  // ---- phase 2: out_row = ar @ v_row; dbuf over s = ct*2 + kw ----
  for (int s = 0; s < 8; ++s){
    int ct = s >> 1, kw = s & 1;
    unsigned short* Acur = (s & 1) ? Av1 : Av0;
    if (s < 7){
      int ct1 = (s + 1) >> 1, kw1 = (s + 1) & 1;
      stage_tile64((s & 1) ? Av0 : Av1,
                   vsrc0 + (size_t)(ct1 * 128) * SS + kw1 * 64, SS, tid);
    }
    if (kw == 0){
      #pragma unroll
      for (int i = 0; i < 4; ++i)
        #pragma unroll
        for (int j = 0; j < 4; ++j) acc[i][j] = (f32x4){0.f, 0.f, 0.f, 0.f};
    }
    __builtin_amdgcn_s_setprio(1);
    #pragma unroll
    for (int ks = 0; ks < 2; ++ks){
      int ch8 = (((ks * 4 + qd) ^ (ln & 7)) * 8);   // swizzled V chunk
      int ko = kw * 64 + ks * 32 + qd * 8;          // ar column offset
      short8 af[4], bfr[4];
      #pragma unroll
      for (int i = 0; i < 4; ++i)
        af[i] = *(const short8*)&Acur[(((wid & 1) * 4 + i) * 16 + ln) * 64 + ch8];
      #pragma unroll
      for (int j = 0; j < 4; ++j)
        bfr[j] = *(const short8*)&El[(((wid >> 1) * 4 + j) * 16 + ln) * 136 + ko];
      #pragma unroll
      for (int i = 0; i < 4; ++i)
        #pragma unroll
        for (int j = 0; j < 4; ++j)
          acc[i][j] = __builtin_amdgcn_mfma_f32_16x16x32_bf16(af[i], bfr[j], acc[i][j], 0, 0, 0);
    }
    __builtin_amdgcn_s_setprio(0);
    if (kw == 1){       // write out_row tile for ct (overwrites vb in place)
      #pragma unroll
      for (int i = 0; i < 4; ++i){
        int c0 = ((wid & 1) * 4 + i) * 16 + qd * 4;
        #pragma unroll
        for (int j = 0; j < 4; ++j){
          int hl = ((wid >> 1) * 4 + j) * 16 + ln;
          #pragma unroll
          for (int r = 0; r < 4; ++r){
            int cg = ct * 128 + c0 + r;
            vb[((size_t)(b * C + cg) * S + w) * S + hl] = f2b(acc[i][j][r]);
          }
        }
      }
    }
    __syncthreads();    // publishes next Av buf; protects Acur reuse
  }
}

// ------- K6: out_col -> oct[b][h][c][w] bf16 ----------------
__global__ __launch_bounds__(256) void k_outcol(
    const unsigned short* __restrict__ vt, const unsigned short* __restrict__ eca,
    unsigned short* __restrict__ oct){
  __shared__ unsigned short Av[128 * 72] __attribute__((aligned(16)));
  __shared__ unsigned short Ba[128 * 72] __attribute__((aligned(16)));
  int blk = blockIdx.x;                 // ((b*128+h)*4 + ct)
  int ct = blk & 3; int bh = blk >> 2;
  int h = bh & 127, b = bh >> 7;
  int tid = threadIdx.x, lane = tid & 63, wid = tid >> 6;
  int qd = lane >> 4, ln = lane & 15;
  f32x4 acc[4][4];
  #pragma unroll
  for (int i = 0; i < 4; ++i)
    #pragma unroll
    for (int j = 0; j < 4; ++j) acc[i][j] = (f32x4){0.f, 0.f, 0.f, 0.f};
  for (int kw = 0; kw < 2; ++kw){
    __syncthreads();
    #pragma unroll
    for (int p = 0; p < 4; ++p){
      int idx = p * 256 + tid;
      int row = idx >> 3, ch = (idx & 7) * 8;
      *(uint4*)&Av[row * 72 + ch] =
        *(const uint4*)(vt + ((size_t)(b * C + ct * 128 + row) * S + h) * S + kw * 64 + ch);
      *(uint4*)&Ba[row * 72 + ch] =
        *(const uint4*)(eca + ((size_t)(b * S + row) * S + h) * S + kw * 64 + ch);
    }
    __syncthreads();
    #pragma unroll
    for (int ks = 0; ks < 2; ++ks){
      int ko = ks * 32 + qd * 8;
      short8 af[4], bfr[4];
      #pragma unroll
      for (int i = 0; i < 4; ++i)
        af[i] = *(const short8*)&Av[(((wid & 1) * 4 + i) * 16 + ln) * 72 + ko];
      #pragma unroll
      for (int j = 0; j < 4; ++j)
        bfr[j] = *(const short8*)&Ba[(((wid >> 1) * 4 + j) * 16 + ln) * 72 + ko];
      #pragma unroll
      for (int i = 0; i < 4; ++i)
        #pragma unroll
        for (int j = 0; j < 4; ++j)
          acc[i][j] = __builtin_amdgcn_mfma_f32_16x16x32_bf16(af[i], bfr[j], acc[i][j], 0, 0, 0);
    }
  }
  #pragma unroll
  for (int i = 0; i < 4; ++i){
    int c0 = ((wid & 1) * 4 + i) * 16 + qd * 4;
    #pragma unroll
    for (int j = 0; j < 4; ++j){
      int wl = ((wid >> 1) * 4 + j) * 16 + ln;
      #pragma unroll
      for (int r = 0; r < 4; ++r){
        int cg = ct * 128 + c0 + r;
        oct[((size_t)(b * S + h) * C + cg) * S + wl] = f2b(acc[i][j][r]);
      }
    }
  }
}

// ------- K7: out = gamma * (orw + transpose(oct)) + x  (single out write) ----
__global__ __launch_bounds__(256) void k_final(
    const unsigned short* __restrict__ oct, const unsigned short* __restrict__ orw,
    const float* __restrict__ x, const float* __restrict__ gamma,
    float* __restrict__ out){
  __shared__ unsigned short T[128 * 130] __attribute__((aligned(16)));
  int blk = blockIdx.x;                 // b*C + c
  int c = blk & 511, b = blk >> 9;
  int tid = threadIdx.x;
  float g = gamma[0];
  #pragma unroll
  for (int p = 0; p < 8; ++p){
    int idx = p * 256 + tid;
    int hh = idx >> 4, ch = (idx & 15) * 8;
    uint4 v = *(const uint4*)(oct + ((size_t)(b * S + hh) * C + c) * S + ch);
    unsigned* d = (unsigned*)&T[PR(hh) * 130 + ch];
    d[0] = v.x; d[1] = v.y; d[2] = v.z; d[3] = v.w;
  }
  __syncthreads();
  #pragma unroll
  for (int p = 0; p < 8; ++p){
    int idx = p * 256 + tid;
    int wv = idx >> 4, hch = (idx & 15) * 8;
    size_t o = ((size_t)(b * C + c) * S + wv) * S + hch;
    uint4 rv = *(const uint4*)(orw + o);
    const unsigned short* rr = (const unsigned short*)&rv;
    float4 x0 = *(const float4*)(x + o);
    float4 x1 = *(const float4*)(x + o + 4);
    float4 o0, o1;
    o0.x = g * (b2f(rr[0]) + b2f(T[PR(hch + 0) * 130 + wv])) + x0.x;
    o0.y = g * (b2f(rr[1]) + b2f(T[PR(hch + 1) * 130 + wv])) + x0.y;
    o0.z = g * (b2f(rr[2]) + b2f(T[PR(hch + 2) * 130 + wv])) + x0.z;
    o0.w = g * (b2f(rr[3]) + b2f(T[PR(hch + 3) * 130 + wv])) + x0.w;
    o1.x = g * (b2f(rr[4]) + b2f(T[PR(hch + 4) * 130 + wv])) + x1.x;
    o1.y = g * (b2f(rr[5]) + b2f(T[PR(hch + 5) * 130 + wv])) + x1.y;
    o1.z = g * (b2f(rr[6]) + b2f(T[PR(hch + 6) * 130 + wv])) + x1.z;
    o1.w = g * (b2f(rr[7]) + b2f(T[PR(hch + 7) * 130 + wv])) + x1.w;
    *(float4*)(out + o) = o0;
    *(float4*)(out + o + 4) = o1;
  }
}

extern "C" void kernel_launch(void* const* d_in, const int* in_sizes, int n_in,
                              void* d_out, int out_size, void* d_ws, size_t ws_size,
                              hipStream_t stream){
  const float* x     = (const float*)d_in[0];
  const float* Wq    = (const float*)d_in[1];
  const float* bq    = (const float*)d_in[2];
  const float* Wk    = (const float*)d_in[3];
  const float* bk    = (const float*)d_in[4];
  const float* Wv    = (const float*)d_in[5];
  const float* bv    = (const float*)d_in[6];
  const float* gamma = (const float*)d_in[7];
  float* out = (float*)d_out;
  char* ws = (char*)d_ws;

  const size_t OFF_WALL = 0;
  const size_t OFF_XP   = 1ull << 20;                    // 134,217,728
  const size_t OFF_QP   = OFF_XP  + 134217728ull;        // 16,777,216
  const size_t OFF_KP   = OFF_QP  + 16777216ull;         // 16,777,216
  const size_t OFF_VB   = OFF_KP  + 16777216ull;         // 134,217,728
  const size_t OFF_VT   = OFF_VB  + 134217728ull;        // 134,217,728
  const size_t OFF_ECA  = OFF_VT  + 134217728ull;        // 33,554,432
  const size_t OFF_OCT  = OFF_XP;                        // alias: xp dead after k_qkv
  const size_t NEED     = OFF_ECA + 33554432ull;         // ~448 MiB
  if (ws_size < NEED) return;                            // cannot run; fail cleanly

  unsigned short* wall = (unsigned short*)(ws + OFF_WALL);
  unsigned short* xp   = (unsigned short*)(ws + OFF_XP);
  unsigned short* qp   = (unsigned short*)(ws + OFF_QP);
  unsigned short* kp   = (unsigned short*)(ws + OFF_KP);
  unsigned short* vb   = (unsigned short*)(ws + OFF_VB);
  unsigned short* vt   = (unsigned short*)(ws + OFF_VT);
  unsigned short* eca  = (unsigned short*)(ws + OFF_ECA);
  unsigned short* oct  = (unsigned short*)(ws + OFF_OCT);
  // orw == vb (in-place overwrite inside k_erow_sm_outrow)

  k_pack_w        <<<1280, 256, 0, stream>>>(Wq, Wk, Wv, wall);
  k_xp            <<<4096, 256, 0, stream>>>(x, xp);
  k_qkv           <<<5120, 256, 0, stream>>>(xp, wall, bq, bk, bv, qp, kp, vb);
  k_tv            <<<4096, 256, 0, stream>>>(vb, vt);          // vt copy BEFORE vb overwrite
  k_ecol          <<<1024, 256, 0, stream>>>(qp, kp, eca);
  k_erow_sm_outrow<<<1024, 256, 0, stream>>>(qp, kp, eca, vb); // ar in LDS; orw = vb in place
  k_outcol        <<<4096, 256, 0, stream>>>(vt, eca, oct);
  k_final         <<<4096, 256, 0, stream>>>(oct, vb, x, gamma, out);
}

// Round 4
// 917.328 us; speedup vs baseline: 1.1983x; 1.0042x over previous
//
#include <hip/hip_runtime.h>
#include <hip/hip_bf16.h>

// Criss-Cross Attention, MI355X. Round 6:
//  - k_qkv: 512 threads / 8 waves (each wave 64x32 output, acc[4][2]) ->
//    16 waves/CU (was 8) at unchanged 64KB LDS; same proven 2-phase dbuf
//    schedule + T2 swizzle + setprio. More waves/SIMD hide the barrier drain.
//  - k_pack_w folded into k_xp (k_xp_pack); k_tv + k_ecol merged (k_tv_ecol):
//    9 -> 7 dispatches.
//  - everything else unchanged from R5 (fused row path, PR transposes).
// B=8, C=512, C8=64, S=128. All MFMA = 16x16x32 bf16 (verified layouts):
//   a/b frag: M[row = lane&15][k = (lane>>4)*8 + j], D = A * B^T
//   D frag:   D[row = (lane>>4)*4 + reg][col = lane&15]

#define S 128
#define SS 16384
#define C 512
#define C8 64
#define NEG_BIG -1000000000.0f

using short8 = __attribute__((ext_vector_type(8))) short;
using f32x4  = __attribute__((ext_vector_type(4))) float;

#define GPTR(p) ((const __attribute__((address_space(1))) void*)(p))
#define LPTR(p) ((__attribute__((address_space(3))) void*)(p))

// row permutation for 128-row LDS transpose tiles (bijective on 0..127)
#define PR(r) ((((r) & 7) << 4) | ((r) >> 3))

__device__ __forceinline__ unsigned short f2b(float f){
  union { float f; unsigned u; } v; v.f = f;
  unsigned r = (v.u + 0x7fffu + ((v.u >> 16) & 1u)) >> 16;
  return (unsigned short)r;
}
__device__ __forceinline__ float b2f(unsigned short h){
  union { unsigned u; float f; } v; v.u = ((unsigned)h) << 16;
  return v.f;
}

// stage one [128][64] bf16 tile (row stride = rstride elems) into LDS,
// chunk-swizzled: LDS chunk gi (16B) receives global chunk (gi&7)^(row&7).
// dest is linear (wave-uniform base + lane*16) as global_load_lds requires.
template<int NT>
__device__ __forceinline__ void stage_tile64(unsigned short* dst,
    const unsigned short* src, size_t rstride, int tid){
  #pragma unroll
  for (int p = 0; p < 1024 / NT; ++p){
    int gi = p * NT + tid;              // 0..1023
    int row = gi >> 3, cc = gi & 7;
    int kc = (cc ^ (row & 7)) * 8;      // inverse-swizzled global chunk
    __builtin_amdgcn_global_load_lds(GPTR(src + (size_t)row * rstride + kc),
                                     LPTR((char*)dst + gi * 16), 16, 0, 0);
  }
}

// ------- K0: x (f32, [b][ci][w][h]) -> xp (bf16, [b][w][h][ci]); also packs
//         Wq|Wk|Wv -> wall[640][512] bf16 (blocks 4096..5375) ----------------
__global__ __launch_bounds__(256) void k_xp_pack(
    const float* __restrict__ x, unsigned short* __restrict__ xp,
    const float* __restrict__ Wq, const float* __restrict__ Wk,
    const float* __restrict__ Wv, unsigned short* __restrict__ wall){
  __shared__ unsigned short T[128 * 130] __attribute__((aligned(16)));
  int blk = blockIdx.x;
  if (blk >= 4096){                     // weight-pack path
    int i = (blk - 4096) * 256 + threadIdx.x;   // 0..327679
    int co = i >> 9, ci = i & (C - 1);
    float v;
    if (co < 64)        v = Wq[co * C + ci];
    else if (co < 128)  v = Wk[(co - 64) * C + ci];
    else                v = Wv[(co - 128) * C + ci];
    wall[i] = f2b(v);
    return;
  }
  int ct = blk & 3; int bw = blk >> 2;
  int w = bw & 127; int b = bw >> 7;
  int tid = threadIdx.x;
  int ci0 = ct * 128;
  const float* xb = x + ((size_t)(b * C + ci0) * S + w) * S;  // + cc*SS + h
  #pragma unroll
  for (int p = 0; p < 16; ++p){
    int idx = p * 256 + tid;            // 0..4095
    int cc = idx >> 5;
    int h4 = (idx & 31) * 4;
    float4 v = *(const float4*)(xb + (size_t)cc * SS + h4);
    unsigned* d = (unsigned*)&T[PR(cc) * 130 + h4];
    d[0] = (unsigned)f2b(v.x) | ((unsigned)f2b(v.y) << 16);
    d[1] = (unsigned)f2b(v.z) | ((unsigned)f2b(v.w) << 16);
  }
  __syncthreads();
  unsigned short* xpb = xp + (size_t)(b * S + w) * S * C + ci0;
  #pragma unroll
  for (int p = 0; p < 8; ++p){
    int idx = p * 256 + tid;            // 0..2047
    int h  = idx >> 4;
    int ch = (idx & 15) * 8;            // cc chunk
    unsigned short tmp[8] __attribute__((aligned(16)));
    #pragma unroll
    for (int j = 0; j < 8; ++j) tmp[j] = T[PR(ch + j) * 130 + h];
    *(uint4*)(xpb + (size_t)h * C + ch) = *(uint4*)tmp;
  }
}

// ---------------- K1: qkv projection GEMM (2-phase dbuf, 512 thr / 8 waves) --
// Swizzled grid (5120): pxsub=blk&7, t=blk>>3, cot=t%5, pxg=t/5, px=pxg*8+pxsub
// Wave (wr = wid&1, wc = wid>>1) owns a 64x32 output sub-tile.
__global__ __launch_bounds__(512) void k_qkv(
    const unsigned short* __restrict__ xp, const unsigned short* __restrict__ wall,
    const float* __restrict__ bq, const float* __restrict__ bk,
    const float* __restrict__ bv,
    unsigned short* __restrict__ qp, unsigned short* __restrict__ kp,
    unsigned short* __restrict__ vb){
  __shared__ unsigned short sm[32768] __attribute__((aligned(16)));  // 65536 B
  // buf k (k=0,1): A at sm + k*16384, B at sm + k*16384 + 8192 (each [128][64])
  unsigned short* Dl = sm;              // alias: [128][136] (17408 shorts)
  int blk = blockIdx.x;
  int pxsub = blk & 7; int t = blk >> 3;
  int cot = t % 5; int pxg = t / 5;
  int pxt = pxg * 8 + pxsub;            // 0..1023
  int w = pxt & 127, b = pxt >> 7;
  int tid = threadIdx.x, lane = tid & 63, wid = tid >> 6;   // wid 0..7
  int wr = wid & 1, wc = wid >> 1;      // wave grid 2 (M) x 4 (N)
  int qd = lane >> 4, ln = lane & 15;
  const unsigned short* asrc0 = wall + (size_t)cot * 128 * C;
  const unsigned short* bsrc0 = xp + (size_t)pxt * 128 * C;
  f32x4 acc[4][2];
  #pragma unroll
  for (int i = 0; i < 4; ++i)
    #pragma unroll
    for (int j = 0; j < 2; ++j) acc[i][j] = (f32x4){0.f, 0.f, 0.f, 0.f};

  // prologue: stage kw=0 into buf0
  stage_tile64<512>(sm,        asrc0, C, tid);
  stage_tile64<512>(sm + 8192, bsrc0, C, tid);
  __syncthreads();                      // drains vmcnt -> buf0 published

  for (int kw = 0; kw < 8; ++kw){
    unsigned short* Acur = sm + (kw & 1) * 16384;
    unsigned short* Bcur = Acur + 8192;
    if (kw < 7){                        // issue next-tile stage BEFORE compute
      unsigned short* Anxt = sm + ((kw + 1) & 1) * 16384;
      stage_tile64<512>(Anxt,        asrc0 + (kw + 1) * 64, C, tid);
      stage_tile64<512>(Anxt + 8192, bsrc0 + (kw + 1) * 64, C, tid);
    }
    __builtin_amdgcn_s_setprio(1);
    #pragma unroll
    for (int ks = 0; ks < 2; ++ks){
      int ch8 = (((ks * 4 + qd) ^ (ln & 7)) * 8);   // swizzled read chunk
      short8 af[4], bfr[2];
      #pragma unroll
      for (int i = 0; i < 4; ++i)
        af[i] = *(const short8*)&Acur[((wr * 4 + i) * 16 + ln) * 64 + ch8];
      #pragma unroll
      for (int j = 0; j < 2; ++j)
        bfr[j] = *(const short8*)&Bcur[((wc * 2 + j) * 16 + ln) * 64 + ch8];
      #pragma unroll
      for (int i = 0; i < 4; ++i)
        #pragma unroll
        for (int j = 0; j < 2; ++j)
          acc[i][j] = __builtin_amdgcn_mfma_f32_16x16x32_bf16(af[i], bfr[j], acc[i][j], 0, 0, 0);
    }
    __builtin_amdgcn_s_setprio(0);
    __syncthreads();   // drains this iter's stage (issued ~compute earlier);
                       // publishes buf[kw+1]; frees buf[kw] for next stage
  }
  // bias + pack into Dl[co][px] (pitch 136), then coalesced global stores
  float bias_[4][4];
  #pragma unroll
  for (int i = 0; i < 4; ++i){
    int co_l0 = (wr * 4 + i) * 16 + qd * 4;
    #pragma unroll
    for (int r = 0; r < 4; ++r){
      int co_l = co_l0 + r;
      bias_[i][r] = (cot == 0) ? (co_l < 64 ? bq[co_l] : bk[co_l - 64])
                               : bv[(cot - 1) * 128 + co_l];
    }
  }
  #pragma unroll
  for (int i = 0; i < 4; ++i){
    int co_l0 = (wr * 4 + i) * 16 + qd * 4;
    #pragma unroll
    for (int j = 0; j < 2; ++j){
      int pxl = (wc * 2 + j) * 16 + ln;
      #pragma unroll
      for (int r = 0; r < 4; ++r)
        Dl[(co_l0 + r) * 136 + pxl] = f2b(acc[i][j][r] + bias_[i][r]);
    }
  }
  __syncthreads();
  if (cot == 0){
    unsigned short* qb = qp + (size_t)(b * S + w) * S * C8;
    unsigned short* kb = kp + (size_t)(b * S + w) * S * C8;
    #pragma unroll
    for (int p = 0; p < 2; ++p){
      int idx = p * 512 + tid;          // 0..1023
      int cch = idx & 7, hh = idx >> 3;
      unsigned short tq[8] __attribute__((aligned(16)));
      unsigned short tk[8] __attribute__((aligned(16)));
      #pragma unroll
      for (int jj = 0; jj < 8; ++jj){
        tq[jj] = Dl[(cch * 8 + jj) * 136 + hh];
        tk[jj] = Dl[(64 + cch * 8 + jj) * 136 + hh];
      }
      *(uint4*)(qb + (size_t)hh * C8 + cch * 8) = *(uint4*)tq;
      *(uint4*)(kb + (size_t)hh * C8 + cch * 8) = *(uint4*)tk;
    }
  } else {
    unsigned short* vbb = vb + ((size_t)(b * C + (cot - 1) * 128) * S + w) * S;
    #pragma unroll
    for (int p = 0; p < 4; ++p){
      int idx = p * 512 + tid;          // 0..2047
      int c_l = idx >> 4, hc = (idx & 15) * 8;
      uint4 v = *(const uint4*)&Dl[c_l * 136 + hc];
      *(uint4*)(vbb + (size_t)c_l * SS + hc) = v;
    }
  }
}

// ------- K2: merged  vb->vt transpose (blocks 0..4095)  +  e_col scores
//         (blocks 4096..5119; masked diag, bf16 out) -------------------------
__global__ __launch_bounds__(256) void k_tv_ecol(
    const unsigned short* __restrict__ vb, unsigned short* __restrict__ vt,
    const unsigned short* __restrict__ qp, const unsigned short* __restrict__ kp,
    unsigned short* __restrict__ eca){
  __shared__ char smu[36864] __attribute__((aligned(16)));
  int blk = blockIdx.x;
  int tid = threadIdx.x;
  if (blk < 4096){                      // ---- transpose path ----
    unsigned short* T = (unsigned short*)smu;       // [128][130]
    const unsigned short* src = vb + (size_t)blk * SS;
    unsigned short* dst = vt + (size_t)blk * SS;
    #pragma unroll
    for (int p = 0; p < 8; ++p){
      int idx = p * 256 + tid;          // 0..2047
      int wv = idx >> 4, ch = (idx & 15) * 8;
      uint4 v = *(const uint4*)(src + wv * S + ch);
      unsigned* d = (unsigned*)&T[PR(wv) * 130 + ch];
      d[0] = v.x; d[1] = v.y; d[2] = v.z; d[3] = v.w;
    }
    __syncthreads();
    #pragma unroll
    for (int p = 0; p < 8; ++p){
      int idx = p * 256 + tid;
      int h = idx >> 4, ch = (idx & 15) * 8;
      unsigned short tmp[8] __attribute__((aligned(16)));
      #pragma unroll
      for (int j = 0; j < 8; ++j) tmp[j] = T[PR(ch + j) * 130 + h];
      *(uint4*)(dst + h * S + ch) = *(uint4*)tmp;
    }
    return;
  }
  // ---- e_col path ----
  unsigned short* Aq = (unsigned short*)smu;          // [128][72]
  unsigned short* Bk = (unsigned short*)(smu + 18432);// [128][72]
  int e = blk - 4096; int h = e & 127, b = e >> 7;
  int lane = tid & 63, wid = tid >> 6;
  int qd = lane >> 4, ln = lane & 15;
  #pragma unroll
  for (int p = 0; p < 4; ++p){
    int idx = p * 256 + tid;
    int row = idx >> 3, ch = (idx & 7) * 8;
    *(uint4*)&Aq[row * 72 + ch] = *(const uint4*)(qp + ((size_t)(b * S + row) * S + h) * C8 + ch);
    *(uint4*)&Bk[row * 72 + ch] = *(const uint4*)(kp + ((size_t)(b * S + row) * S + h) * C8 + ch);
  }
  __syncthreads();
  f32x4 acc[4][4];
  #pragma unroll
  for (int i = 0; i < 4; ++i)
    #pragma unroll
    for (int j = 0; j < 4; ++j) acc[i][j] = (f32x4){0.f, 0.f, 0.f, 0.f};
  #pragma unroll
  for (int ks = 0; ks < 2; ++ks){
    int ko = ks * 32 + qd * 8;
    short8 af[4], bfr[4];
    #pragma unroll
    for (int i = 0; i < 4; ++i)
      af[i] = *(const short8*)&Aq[(((wid & 1) * 4 + i) * 16 + ln) * 72 + ko];
    #pragma unroll
    for (int j = 0; j < 4; ++j)
      bfr[j] = *(const short8*)&Bk[(((wid >> 1) * 4 + j) * 16 + ln) * 72 + ko];
    #pragma unroll
    for (int i = 0; i < 4; ++i)
      #pragma unroll
      for (int j = 0; j < 4; ++j)
        acc[i][j] = __builtin_amdgcn_mfma_f32_16x16x32_bf16(af[i], bfr[j], acc[i][j], 0, 0, 0);
  }
  #pragma unroll
  for (int i = 0; i < 4; ++i){
    int w0 = (((wid & 1) * 4 + i) * 16) + qd * 4;
    #pragma unroll
    for (int j = 0; j < 4; ++j){
      int ug = ((wid >> 1) * 4 + j) * 16 + ln;
      #pragma unroll
      for (int r = 0; r < 4; ++r){
        int wg = w0 + r;
        float val = acc[i][j][r];
        if (wg == ug) val = NEG_BIG;
        eca[((size_t)(b * S + wg) * S + h) * S + ug] = f2b(val);
      }
    }
  }
}

// ------- K3: row scores + joint softmax + out_row PV GEMM (fused) -----------
// Per (b,w): e_row via MFMA -> El; joint softmax over [eca | El]; ac -> eca
// (in place, for k_outcol), ar normalized IN PLACE into El (LDS only);
// then out_row = ar @ v_row staged from vb; result OVERWRITES vb in place
// (block (b,w) reads and writes only vb[b][:][w][:]; per-ct read-then-write).
__global__ __launch_bounds__(256) void k_erow_sm_outrow(
    const unsigned short* __restrict__ qp, const unsigned short* __restrict__ kp,
    unsigned short* __restrict__ eca, unsigned short* vb){
  __shared__ char sm[71680] __attribute__((aligned(16)));
  unsigned short* Aq  = (unsigned short*)sm;             // [128][72] (phase 1)
  unsigned short* Bk  = (unsigned short*)(sm + 18432);   // [128][72] (phase 1)
  unsigned short* El  = (unsigned short*)sm;             // alias: [128][136]
  unsigned short* Av0 = (unsigned short*)(sm + 36864);   // [128][64] swizzled
  unsigned short* Av1 = (unsigned short*)(sm + 53248);   // [128][64] swizzled
  float* redm = (float*)(sm + 69632);                    // [256]
  float* reds = (float*)(sm + 70656);                    // [256]
  int blk = blockIdx.x; int w = blk & 127, b = blk >> 7;
  int tid = threadIdx.x, lane = tid & 63, wid = tid >> 6;
  int qd = lane >> 4, ln = lane & 15;
  size_t tb = (size_t)(b * S + w) * SS;                  // eca tile base (elems)
  const unsigned short* vsrc0 = vb + (size_t)(b * C) * SS + (size_t)w * S;

  // ---- phase 1: stage q/k, plus prefetch first V tile into Av0 ----
  {
    const unsigned short* qsrc = qp + (size_t)(b * S + w) * S * C8;
    const unsigned short* ksrc = kp + (size_t)(b * S + w) * S * C8;
    #pragma unroll
    for (int p = 0; p < 4; ++p){
      int idx = p * 256 + tid;
      int row = idx >> 3, ch = (idx & 7) * 8;
      *(uint4*)&Aq[row * 72 + ch] = *(const uint4*)(qsrc + row * C8 + ch);
      *(uint4*)&Bk[row * 72 + ch] = *(const uint4*)(ksrc + row * C8 + ch);
    }
  }
  stage_tile64<256>(Av0, vsrc0, SS, tid); // s=0 (ct=0, kw=0), hides under phase 1
  __syncthreads();
  f32x4 acc[4][4];
  #pragma unroll
  for (int i = 0; i < 4; ++i)
    #pragma unroll
    for (int j = 0; j < 4; ++j) acc[i][j] = (f32x4){0.f, 0.f, 0.f, 0.f};
  #pragma unroll
  for (int ks = 0; ks < 2; ++ks){
    int ko = ks * 32 + qd * 8;
    short8 af[4], bfr[4];
    #pragma unroll
    for (int i = 0; i < 4; ++i)
      af[i] = *(const short8*)&Aq[(((wid & 1) * 4 + i) * 16 + ln) * 72 + ko];
    #pragma unroll
    for (int j = 0; j < 4; ++j)
      bfr[j] = *(const short8*)&Bk[(((wid >> 1) * 4 + j) * 16 + ln) * 72 + ko];
    #pragma unroll
    for (int i = 0; i < 4; ++i)
      #pragma unroll
      for (int j = 0; j < 4; ++j)
        acc[i][j] = __builtin_amdgcn_mfma_f32_16x16x32_bf16(af[i], bfr[j], acc[i][j], 0, 0, 0);
  }
  __syncthreads();     // done with Aq/Bk; El may now alias them
  #pragma unroll
  for (int i = 0; i < 4; ++i){
    int h0 = ((wid & 1) * 4 + i) * 16 + qd * 4;
    #pragma unroll
    for (int j = 0; j < 4; ++j){
      int ul = ((wid >> 1) * 4 + j) * 16 + ln;
      #pragma unroll
      for (int r = 0; r < 4; ++r)
        El[(h0 + r) * 136 + ul] = f2b(acc[i][j][r]);
    }
  }
  __syncthreads();
  // ---- joint softmax over 256 = [col(eca) | row(El)] per h; 2 thr per h ----
  {
    int h = tid >> 1, half = tid & 1;
    const uint4* src4 = (half == 0) ? (const uint4*)(eca + tb + (size_t)h * S)
                                    : (const uint4*)&El[h * 136];
    float mx = -3.0e38f;
    #pragma unroll 4
    for (int u = 0; u < 16; ++u){
      uint4 v = src4[u];
      const unsigned short* e = (const unsigned short*)&v;
      #pragma unroll
      for (int jj = 0; jj < 8; ++jj) mx = fmaxf(mx, b2f(e[jj]));
    }
    redm[tid] = mx;
    __syncthreads();
    float m = fmaxf(mx, redm[tid ^ 1]);
    float s = 0.f;
    #pragma unroll 4
    for (int u = 0; u < 16; ++u){
      uint4 v = src4[u];
      const unsigned short* e = (const unsigned short*)&v;
      #pragma unroll
      for (int jj = 0; jj < 8; ++jj) s += __expf(b2f(e[jj]) - m);
    }
    reds[tid] = s;
    __syncthreads();
    float inv = 1.0f / (s + reds[tid ^ 1]);
    uint4* dst4 = (half == 0) ? (uint4*)(eca + tb + (size_t)h * S)
                              : (uint4*)&El[h * 136];       // ar in place
    #pragma unroll 4
    for (int u = 0; u < 16; ++u){
      uint4 v = src4[u];
      const unsigned short* e = (const unsigned short*)&v;
      unsigned short o[8] __attribute__((aligned(16)));
      #pragma unroll
      for (int jj = 0; jj < 8; ++jj) o[jj] = f2b(__expf(b2f(e[jj]) - m) * inv);
      dst4[u] = *(uint4*)o;
    }
  }
  __syncthreads();      // El now holds normalized ar[128 h][128 u]

  // ---- phase 2: out_row = ar @ v_row; dbuf over s = ct*2 + kw ----
  for (int s = 0; s < 8; ++s){
    int ct = s >> 1, kw = s & 1;
    unsigned short* Acur = (s & 1) ? Av1 : Av0;
    if (s < 7){
      int ct1 = (s + 1) >> 1, kw1 = (s + 1) & 1;
      stage_tile64<256>((s & 1) ? Av0 : Av1,
                        vsrc0 + (size_t)(ct1 * 128) * SS + kw1 * 64, SS, tid);
    }
    if (kw == 0){
      #pragma unroll
      for (int i = 0; i < 4; ++i)
        #pragma unroll
        for (int j = 0; j < 4; ++j) acc[i][j] = (f32x4){0.f, 0.f, 0.f, 0.f};
    }
    __builtin_amdgcn_s_setprio(1);
    #pragma unroll
    for (int ks = 0; ks < 2; ++ks){
      int ch8 = (((ks * 4 + qd) ^ (ln & 7)) * 8);   // swizzled V chunk
      int ko = kw * 64 + ks * 32 + qd * 8;          // ar column offset
      short8 af[4], bfr[4];
      #pragma unroll
      for (int i = 0; i < 4; ++i)
        af[i] = *(const short8*)&Acur[(((wid & 1) * 4 + i) * 16 + ln) * 64 + ch8];
      #pragma unroll
      for (int j = 0; j < 4; ++j)
        bfr[j] = *(const short8*)&El[(((wid >> 1) * 4 + j) * 16 + ln) * 136 + ko];
      #pragma unroll
      for (int i = 0; i < 4; ++i)
        #pragma unroll
        for (int j = 0; j < 4; ++j)
          acc[i][j] = __builtin_amdgcn_mfma_f32_16x16x32_bf16(af[i], bfr[j], acc[i][j], 0, 0, 0);
    }
    __builtin_amdgcn_s_setprio(0);
    if (kw == 1){       // write out_row tile for ct (overwrites vb in place)
      #pragma unroll
      for (int i = 0; i < 4; ++i){
        int c0 = ((wid & 1) * 4 + i) * 16 + qd * 4;
        #pragma unroll
        for (int j = 0; j < 4; ++j){
          int hl = ((wid >> 1) * 4 + j) * 16 + ln;
          #pragma unroll
          for (int r = 0; r < 4; ++r){
            int cg = ct * 128 + c0 + r;
            vb[((size_t)(b * C + cg) * S + w) * S + hl] = f2b(acc[i][j][r]);
          }
        }
      }
    }
    __syncthreads();    // publishes next Av buf; protects Acur reuse
  }
}

// ------- K4: out_col -> oct[b][h][c][w] bf16 ----------------
__global__ __launch_bounds__(256) void k_outcol(
    const unsigned short* __restrict__ vt, const unsigned short* __restrict__ eca,
    unsigned short* __restrict__ oct){
  __shared__ unsigned short Av[128 * 72] __attribute__((aligned(16)));
  __shared__ unsigned short Ba[128 * 72] __attribute__((aligned(16)));
  int blk = blockIdx.x;                 // ((b*128+h)*4 + ct)
  int ct = blk & 3; int bh = blk >> 2;
  int h = bh & 127, b = bh >> 7;
  int tid = threadIdx.x, lane = tid & 63, wid = tid >> 6;
  int qd = lane >> 4, ln = lane & 15;
  f32x4 acc[4][4];
  #pragma unroll
  for (int i = 0; i < 4; ++i)
    #pragma unroll
    for (int j = 0; j < 4; ++j) acc[i][j] = (f32x4){0.f, 0.f, 0.f, 0.f};
  for (int kw = 0; kw < 2; ++kw){
    __syncthreads();
    #pragma unroll
    for (int p = 0; p < 4; ++p){
      int idx = p * 256 + tid;
      int row = idx >> 3, ch = (idx & 7) * 8;
      *(uint4*)&Av[row * 72 + ch] =
        *(const uint4*)(vt + ((size_t)(b * C + ct * 128 + row) * S + h) * S + kw * 64 + ch);
      *(uint4*)&Ba[row * 72 + ch] =
        *(const uint4*)(eca + ((size_t)(b * S + row) * S + h) * S + kw * 64 + ch);
    }
    __syncthreads();
    #pragma unroll
    for (int ks = 0; ks < 2; ++ks){
      int ko = ks * 32 + qd * 8;
      short8 af[4], bfr[4];
      #pragma unroll
      for (int i = 0; i < 4; ++i)
        af[i] = *(const short8*)&Av[(((wid & 1) * 4 + i) * 16 + ln) * 72 + ko];
      #pragma unroll
      for (int j = 0; j < 4; ++j)
        bfr[j] = *(const short8*)&Ba[(((wid >> 1) * 4 + j) * 16 + ln) * 72 + ko];
      #pragma unroll
      for (int i = 0; i < 4; ++i)
        #pragma unroll
        for (int j = 0; j < 4; ++j)
          acc[i][j] = __builtin_amdgcn_mfma_f32_16x16x32_bf16(af[i], bfr[j], acc[i][j], 0, 0, 0);
    }
  }
  #pragma unroll
  for (int i = 0; i < 4; ++i){
    int c0 = ((wid & 1) * 4 + i) * 16 + qd * 4;
    #pragma unroll
    for (int j = 0; j < 4; ++j){
      int wl = ((wid >> 1) * 4 + j) * 16 + ln;
      #pragma unroll
      for (int r = 0; r < 4; ++r){
        int cg = ct * 128 + c0 + r;
        oct[((size_t)(b * S + h) * C + cg) * S + wl] = f2b(acc[i][j][r]);
      }
    }
  }
}

// ------- K5: out = gamma * (orw + transpose(oct)) + x  (single out write) ----
__global__ __launch_bounds__(256) void k_final(
    const unsigned short* __restrict__ oct, const unsigned short* __restrict__ orw,
    const float* __restrict__ x, const float* __restrict__ gamma,
    float* __restrict__ out){
  __shared__ unsigned short T[128 * 130] __attribute__((aligned(16)));
  int blk = blockIdx.x;                 // b*C + c
  int c = blk & 511, b = blk >> 9;
  int tid = threadIdx.x;
  float g = gamma[0];
  #pragma unroll
  for (int p = 0; p < 8; ++p){
    int idx = p * 256 + tid;
    int hh = idx >> 4, ch = (idx & 15) * 8;
    uint4 v = *(const uint4*)(oct + ((size_t)(b * S + hh) * C + c) * S + ch);
    unsigned* d = (unsigned*)&T[PR(hh) * 130 + ch];
    d[0] = v.x; d[1] = v.y; d[2] = v.z; d[3] = v.w;
  }
  __syncthreads();
  #pragma unroll
  for (int p = 0; p < 8; ++p){
    int idx = p * 256 + tid;
    int wv = idx >> 4, hch = (idx & 15) * 8;
    size_t o = ((size_t)(b * C + c) * S + wv) * S + hch;
    uint4 rv = *(const uint4*)(orw + o);
    const unsigned short* rr = (const unsigned short*)&rv;
    float4 x0 = *(const float4*)(x + o);
    float4 x1 = *(const float4*)(x + o + 4);
    float4 o0, o1;
    o0.x = g * (b2f(rr[0]) + b2f(T[PR(hch + 0) * 130 + wv])) + x0.x;
    o0.y = g * (b2f(rr[1]) + b2f(T[PR(hch + 1) * 130 + wv])) + x0.y;
    o0.z = g * (b2f(rr[2]) + b2f(T[PR(hch + 2) * 130 + wv])) + x0.z;
    o0.w = g * (b2f(rr[3]) + b2f(T[PR(hch + 3) * 130 + wv])) + x0.w;
    o1.x = g * (b2f(rr[4]) + b2f(T[PR(hch + 4) * 130 + wv])) + x1.x;
    o1.y = g * (b2f(rr[5]) + b2f(T[PR(hch + 5) * 130 + wv])) + x1.y;
    o1.z = g * (b2f(rr[6]) + b2f(T[PR(hch + 6) * 130 + wv])) + x1.z;
    o1.w = g * (b2f(rr[7]) + b2f(T[PR(hch + 7) * 130 + wv])) + x1.w;
    *(float4*)(out + o) = o0;
    *(float4*)(out + o + 4) = o1;
  }
}

extern "C" void kernel_launch(void* const* d_in, const int* in_sizes, int n_in,
                              void* d_out, int out_size, void* d_ws, size_t ws_size,
                              hipStream_t stream){
  const float* x     = (const float*)d_in[0];
  const float* Wq    = (const float*)d_in[1];
  const float* bq    = (const float*)d_in[2];
  const float* Wk    = (const float*)d_in[3];
  const float* bk    = (const float*)d_in[4];
  const float* Wv    = (const float*)d_in[5];
  const float* bv    = (const float*)d_in[6];
  const float* gamma = (const float*)d_in[7];
  float* out = (float*)d_out;
  char* ws = (char*)d_ws;

  const size_t OFF_WALL = 0;
  const size_t OFF_XP   = 1ull << 20;                    // 134,217,728
  const size_t OFF_QP   = OFF_XP  + 134217728ull;        // 16,777,216
  const size_t OFF_KP   = OFF_QP  + 16777216ull;         // 16,777,216
  const size_t OFF_VB   = OFF_KP  + 16777216ull;         // 134,217,728
  const size_t OFF_VT   = OFF_VB  + 134217728ull;        // 134,217,728
  const size_t OFF_ECA  = OFF_VT  + 134217728ull;        // 33,554,432
  const size_t OFF_OCT  = OFF_XP;                        // alias: xp dead after k_qkv
  const size_t NEED     = OFF_ECA + 33554432ull;         // ~448 MiB
  if (ws_size < NEED) return;                            // cannot run; fail cleanly

  unsigned short* wall = (unsigned short*)(ws + OFF_WALL);
  unsigned short* xp   = (unsigned short*)(ws + OFF_XP);
  unsigned short* qp   = (unsigned short*)(ws + OFF_QP);
  unsigned short* kp   = (unsigned short*)(ws + OFF_KP);
  unsigned short* vb   = (unsigned short*)(ws + OFF_VB);
  unsigned short* vt   = (unsigned short*)(ws + OFF_VT);
  unsigned short* eca  = (unsigned short*)(ws + OFF_ECA);
  unsigned short* oct  = (unsigned short*)(ws + OFF_OCT);
  // orw == vb (in-place overwrite inside k_erow_sm_outrow)

  k_xp_pack       <<<5376, 256, 0, stream>>>(x, xp, Wq, Wk, Wv, wall);
  k_qkv           <<<5120, 512, 0, stream>>>(xp, wall, bq, bk, bv, qp, kp, vb);
  k_tv_ecol       <<<5120, 256, 0, stream>>>(vb, vt, qp, kp, eca);
  k_erow_sm_outrow<<<1024, 256, 0, stream>>>(qp, kp, eca, vb); // ar in LDS; orw = vb in place
  k_outcol        <<<4096, 256, 0, stream>>>(vt, eca, oct);
  k_final         <<<4096, 256, 0, stream>>>(oct, vb, x, gamma, out);
}